// Round 2
// baseline (2515.389 us; speedup 1.0000x reference)
//
#include <hip/hip_runtime.h>
#include <hip/hip_bf16.h>

typedef __hip_bfloat16 bf16;
#define FDIM 64
#define SNIFF_THRESH 100

__device__ __forceinline__ float b2f(bf16 v) { return __bfloat162float(v); }
__device__ __forceinline__ bf16 f2b(float v) { return __float2bfloat16(v); }
__device__ __forceinline__ float inv_sqrt_pos(float d) { return d > 0.f ? rsqrtf(d) : 0.f; }

// ---------- dtype sniffing & canonicalization ----------
// If x is really fp32 read as 16-bit halves, the low halves are random mantissa
// bits: ~1/256 match the Inf/NaN exponent pattern. True bf16 N(0,1) data: zero.
__global__ void k_sniff(const unsigned short* __restrict__ xs, int n, int* __restrict__ cnt) {
  int i = blockIdx.x * 256 + threadIdx.x;
  if (i < n) {
    unsigned short v = xs[i];
    if ((v & 0x7F80) == 0x7F80) atomicAdd(cnt, 1);
  }
}

__global__ void k_convert_x(const void* __restrict__ xin, bf16* __restrict__ xb,
                            const int* __restrict__ cnt, int n) {
  int i = blockIdx.x * 256 + threadIdx.x;
  if (i >= n) return;
  if (*cnt > SNIFF_THRESH) xb[i] = f2b(((const float*)xin)[i]);
  else                     xb[i] = ((const bf16*)xin)[i];
}

__global__ void k_convert_w(const void* W0, const void* W1, const void* W2,
                            const void* W3, const void* W4, const void* W5,
                            const void* c0, const void* c1, const void* c2,
                            const void* c3, const void* c4, const void* c5,
                            bf16* __restrict__ wb, bf16* __restrict__ bbv,
                            const int* __restrict__ cnt) {
  int t = blockIdx.x * 256 + threadIdx.x;
  const void* Ws[6] = {W0, W1, W2, W3, W4, W5};
  const void* Bs[6] = {c0, c1, c2, c3, c4, c5};
  bool fp = (*cnt > SNIFF_THRESH);
  if (t < 6 * 4096) {
    int i = t >> 12, o = t & 4095;
    wb[t] = fp ? f2b(((const float*)Ws[i])[o]) : ((const bf16*)Ws[i])[o];
  } else if (t < 6 * 4096 + 6 * 64) {
    int u = t - 6 * 4096;
    int i = u >> 6, o = u & 63;
    bbv[u] = fp ? f2b(((const float*)Bs[i])[o]) : ((const bf16*)Bs[i])[o];
  }
}

// ---------- setup kernels ----------
__global__ void k_degrees(const int* __restrict__ row, const int* __restrict__ col,
                          int* __restrict__ dout, int* __restrict__ din, int E) {
  int e = blockIdx.x * 256 + threadIdx.x;
  if (e < E) {
    atomicAdd(&dout[row[e]], 1);
    atomicAdd(&din[col[e]], 1);
  }
}

__global__ void k_m4(const int* __restrict__ row, const int* __restrict__ col,
                     const int* __restrict__ dout, const int* __restrict__ din,
                     float* __restrict__ mAAt, float* __restrict__ mAtA,
                     float* __restrict__ mAAo, float* __restrict__ mAAi, int E) {
  int e = blockIdx.x * 256 + threadIdx.x;
  if (e < E) {
    int r = row[e], c = col[e];
    atomicAdd(&mAAt[r], (float)din[c]);   // Av(d_in)
    atomicAdd(&mAtA[c], (float)dout[r]);  // Atv(d_out)
    atomicAdd(&mAAo[r], (float)dout[c]);  // Av(d_out)
    atomicAdd(&mAAi[c], (float)din[r]);   // Atv(d_in)
  }
}

__global__ void k_scan_block(const int* __restrict__ in, int* __restrict__ out,
                             int* __restrict__ part, int n) {
  __shared__ int sm[256];
  int tid = threadIdx.x;
  int i = blockIdx.x * 256 + tid;
  int v = (i < n) ? in[i] : 0;
  sm[tid] = v;
  __syncthreads();
  for (int d = 1; d < 256; d <<= 1) {
    int t = (tid >= d) ? sm[tid - d] : 0;
    __syncthreads();
    if (tid >= d) sm[tid] += t;
    __syncthreads();
  }
  if (i < n) out[i] = sm[tid] - v;  // exclusive within block
  if (tid == 255) part[blockIdx.x] = sm[255];
}

// single-block exclusive scan of up to 1024 partials
__global__ void k_scan_part(int* part, int nb) {
  __shared__ int sm[1024];
  int tid = threadIdx.x;
  int v = (tid < nb) ? part[tid] : 0;
  sm[tid] = v;
  __syncthreads();
  for (int d = 1; d < 1024; d <<= 1) {
    int t = (tid >= d) ? sm[tid - d] : 0;
    __syncthreads();
    if (tid >= d) sm[tid] += t;
    __syncthreads();
  }
  if (tid < nb) part[tid] = sm[tid] - v;
}

__global__ void k_scan_add(int* __restrict__ out, const int* __restrict__ part, int n) {
  int i = blockIdx.x * 256 + threadIdx.x;
  if (i < n) out[i] += part[blockIdx.x];
}

__global__ void k_scales(const int* __restrict__ dout, const int* __restrict__ din,
                         const float* __restrict__ mAAt, const float* __restrict__ mAtA,
                         const float* __restrict__ mAAo, const float* __restrict__ mAAi,
                         float* iso, float* isi, float* sAAt, float* sAtA,
                         float* sAAo, float* sAAi, int n) {
  int i = blockIdx.x * 256 + threadIdx.x;
  if (i < n) {
    iso[i]  = inv_sqrt_pos((float)dout[i]);
    isi[i]  = inv_sqrt_pos((float)din[i]);
    sAAt[i] = inv_sqrt_pos(mAAt[i]);
    sAtA[i] = inv_sqrt_pos(mAtA[i]);
    sAAo[i] = inv_sqrt_pos(mAAo[i]);
    sAAi[i] = inv_sqrt_pos(mAAi[i]);
  }
}

__global__ void k_scatter(const int* __restrict__ row, const int* __restrict__ col,
                          const int* __restrict__ roff, const int* __restrict__ coff,
                          int* rcur, int* ccur,
                          int* __restrict__ adj_out, int* __restrict__ adj_in, int E) {
  int e = blockIdx.x * 256 + threadIdx.x;
  if (e < E) {
    int r = row[e], c = col[e];
    int p = atomicAdd(&rcur[r], 1);
    adj_out[roff[r] + p] = c;
    int q = atomicAdd(&ccur[c], 1);
    adj_in[coff[c] + q] = r;
  }
}

// ---------- SpMM passes (gather, one wave per node, lane = feature) ----------
__global__ __launch_bounds__(256)
void k_pass3(const int* __restrict__ off, const int* __restrict__ deg,
             const int* __restrict__ adj, const bf16* __restrict__ x,
             const float* __restrict__ s0, const float* __restrict__ s1,
             const float* __restrict__ s2, const float* __restrict__ wsA,
             bf16* __restrict__ outA, bf16* __restrict__ outB, bf16* __restrict__ outC,
             int N) {
  int wid = (blockIdx.x * 256 + threadIdx.x) >> 6;
  int lane = threadIdx.x & 63;
  if (wid >= N) return;
  int o = off[wid], d = deg[wid];
  float a0 = 0.f, a1 = 0.f, a2 = 0.f;
  for (int e = 0; e < d; e++) {
    int nb = adj[o + e];
    float f = b2f(x[nb * FDIM + lane]);
    a0 += s0[nb] * f;
    a1 += s1[nb] * f;
    a2 += s2[nb] * f;
  }
  outA[wid * FDIM + lane] = f2b(a0 * wsA[wid]);
  outB[wid * FDIM + lane] = f2b(a1);
  outC[wid * FDIM + lane] = f2b(a2);
}

// out[n] = ws[n] * sum over neighbors of in[nb]
__global__ __launch_bounds__(256)
void k_pass1(const int* __restrict__ off, const int* __restrict__ deg,
             const int* __restrict__ adj, const bf16* __restrict__ in,
             const float* __restrict__ ws, bf16* __restrict__ out, int N) {
  int wid = (blockIdx.x * 256 + threadIdx.x) >> 6;
  int lane = threadIdx.x & 63;
  if (wid >= N) return;
  int o = off[wid], d = deg[wid];
  float a = 0.f;
  for (int e = 0; e < d; e++) {
    int nb = adj[o + e];
    a += b2f(in[nb * FDIM + lane]);
  }
  out[wid * FDIM + lane] = f2b(a * ws[wid]);
}

// ---------- final fused 6-GEMM: out = 0.75*(sum_i H_i @ W_i + sum_i b_i) ----------
__global__ __launch_bounds__(256)
void k_final(const bf16* __restrict__ H0, const bf16* __restrict__ H1,
             const bf16* __restrict__ H2, const bf16* __restrict__ H3,
             const bf16* __restrict__ H4, const bf16* __restrict__ H5,
             const bf16* __restrict__ wb, const bf16* __restrict__ bbv,
             void* __restrict__ outv, const int* __restrict__ cnt, int N) {
  __shared__ bf16 Wl[6 * 64 * 64];
  __shared__ float bs[64];
  int tid = threadIdx.x;
  for (int t = tid; t < 6 * 4096; t += 256) Wl[t] = wb[t];
  if (tid < 64) {
    float s = 0.f;
    for (int i = 0; i < 6; i++) s += b2f(bbv[i * 64 + tid]);
    bs[tid] = s;
  }
  __syncthreads();

  bool fp = (*cnt > SNIFF_THRESH);
  const bf16* Hs[6] = {H0, H1, H2, H3, H4, H5};
  int wave = tid >> 6;
  int j = tid & 63;
  int base = blockIdx.x * 64 + wave * 16;  // 64 nodes/block, 16/wave
  for (int it = 0; it < 16; it++) {
    int n = base + it;
    if (n >= N) break;
    float acc = bs[j];
    for (int i = 0; i < 6; i++) {
      float h = b2f(Hs[i][n * FDIM + j]);  // lane j holds H_i[n, j]
      #pragma unroll
      for (int k = 0; k < 64; k++) {
        float hk = __shfl(h, k, 64);
        acc += hk * b2f(Wl[i * 4096 + k * 64 + j]);
      }
    }
    float val = 0.75f * acc;
    if (fp) ((float*)outv)[n * FDIM + j] = val;
    else    ((bf16*)outv)[n * FDIM + j] = f2b(val);
  }
}

// ---------- host ----------
extern "C" void kernel_launch(void* const* d_in, const int* in_sizes, int n_in,
                              void* d_out, int out_size, void* d_ws, size_t ws_size,
                              hipStream_t stream) {
  const void* x = d_in[0];
  const int* ei = (const int*)d_in[1];
  int NX = in_sizes[0];          // N*FDIM elements
  int N = NX / FDIM;
  int E = in_sizes[1] / 2;
  const int* row = ei;
  const int* col = ei + E;

  // bump allocator over d_ws, 256B aligned
  char* p = (char*)d_ws;
  auto alloc = [&](size_t bytes) {
    bytes = (bytes + 255) & ~(size_t)255;
    char* r = p; p += bytes; return r;
  };

  // zero-init region (contiguous from d_ws start)
  int*   cnt    = (int*)alloc(4);
  int*   dout_i = (int*)alloc((size_t)N * 4);
  int*   din_i  = (int*)alloc((size_t)N * 4);
  int*   rcur   = (int*)alloc((size_t)N * 4);
  int*   ccur   = (int*)alloc((size_t)N * 4);
  float* mAAt   = (float*)alloc((size_t)N * 4);
  float* mAtA   = (float*)alloc((size_t)N * 4);
  float* mAAo   = (float*)alloc((size_t)N * 4);
  float* mAAi   = (float*)alloc((size_t)N * 4);
  size_t zbytes = (size_t)(p - (char*)d_ws);

  int* roff  = (int*)alloc((size_t)N * 4);
  int* coff  = (int*)alloc((size_t)N * 4);
  int* partA = (int*)alloc(1024 * 4);
  int* partB = (int*)alloc(1024 * 4);
  float* iso  = (float*)alloc((size_t)N * 4);
  float* isi  = (float*)alloc((size_t)N * 4);
  float* sAAt = (float*)alloc((size_t)N * 4);
  float* sAtA = (float*)alloc((size_t)N * 4);
  float* sAAo = (float*)alloc((size_t)N * 4);
  float* sAAi = (float*)alloc((size_t)N * 4);
  int* adj_out = (int*)alloc((size_t)E * 4);
  int* adj_in  = (int*)alloc((size_t)E * 4);
  bf16* xb  = (bf16*)alloc((size_t)NX * 2);       // canonical bf16 x
  bf16* wb  = (bf16*)alloc((size_t)6 * 4096 * 2); // canonical bf16 W's
  bf16* bbv = (bf16*)alloc((size_t)6 * 64 * 2);   // canonical bf16 b's
  size_t fb = (size_t)N * FDIM * sizeof(bf16);
  bf16* B1 = (bf16*)alloc(fb);
  bf16* B2 = (bf16*)alloc(fb);
  bf16* B3 = (bf16*)alloc(fb);
  bf16* B4 = (bf16*)alloc(fb);
  bf16* B5 = (bf16*)alloc(fb);
  bf16* B6 = (bf16*)alloc(fb);
  bf16* B7 = (bf16*)alloc(fb);

  hipMemsetAsync(d_ws, 0, zbytes, stream);

  int gX = (NX + 255) / 256;
  int gE = (E + 255) / 256;
  int gN = (N + 255) / 256;  // scan blocks
  int gW = (N + 3) / 4;      // wave-per-node kernels
  int gF = (N + 63) / 64;    // final

  // dtype canonicalization
  k_sniff<<<gX, 256, 0, stream>>>((const unsigned short*)x, NX, cnt);
  k_convert_x<<<gX, 256, 0, stream>>>(x, xb, cnt, NX);
  k_convert_w<<<98, 256, 0, stream>>>(d_in[2], d_in[4], d_in[6], d_in[8], d_in[10], d_in[12],
                                      d_in[3], d_in[5], d_in[7], d_in[9], d_in[11], d_in[13],
                                      wb, bbv, cnt);

  // degrees, CSR build, scales
  k_degrees<<<gE, 256, 0, stream>>>(row, col, dout_i, din_i, E);
  k_m4<<<gE, 256, 0, stream>>>(row, col, dout_i, din_i, mAAt, mAtA, mAAo, mAAi, E);
  k_scan_block<<<gN, 256, 0, stream>>>(dout_i, roff, partA, N);
  k_scan_part<<<1, 1024, 0, stream>>>(partA, gN);
  k_scan_add<<<gN, 256, 0, stream>>>(roff, partA, N);
  k_scan_block<<<gN, 256, 0, stream>>>(din_i, coff, partB, N);
  k_scan_part<<<1, 1024, 0, stream>>>(partB, gN);
  k_scan_add<<<gN, 256, 0, stream>>>(coff, partB, N);
  k_scales<<<gN, 256, 0, stream>>>(dout_i, din_i, mAAt, mAtA, mAAo, mAAi,
                                   iso, isi, sAAt, sAtA, sAAo, sAAi, N);
  k_scatter<<<gE, 256, 0, stream>>>(row, col, roff, coff, rcur, ccur, adj_out, adj_in, E);

  // Pass A (Av, out-CSR): B1=P1=iso*Av(isi*x), B2=Q2=Av(sAtA*x), B3=R1=Av(sAAi*x)
  k_pass3<<<gW, 256, 0, stream>>>(roff, dout_i, adj_out, xb, isi, sAtA, sAAi, iso,
                                  B1, B2, B3, N);
  // Pass B (Atv, in-CSR): B4=P2=isi*Atv(iso*x), B5=Q1=Atv(sAAt*x), B6=R2=Atv(sAAo*x)
  k_pass3<<<gW, 256, 0, stream>>>(coff, din_i, adj_in, xb, iso, sAAt, sAAo, isi,
                                  B4, B5, B6, N);
  // C1 (Av):  S0 = sAAt*Av(Q1=B5) -> B7   (B5 dead after)
  k_pass1<<<gW, 256, 0, stream>>>(roff, dout_i, adj_out, B5, sAAt, B7, N);
  // C2 (Av):  S2 = sAAo*Av(R1=B3) -> B5   (B3 dead after)
  k_pass1<<<gW, 256, 0, stream>>>(roff, dout_i, adj_out, B3, sAAo, B5, N);
  // D1 (Atv): S1 = sAtA*Atv(Q2=B2) -> B3  (B2 dead after)
  k_pass1<<<gW, 256, 0, stream>>>(coff, din_i, adj_in, B2, sAtA, B3, N);
  // D2 (Atv): S3 = sAAi*Atv(R2=B6) -> B2
  k_pass1<<<gW, 256, 0, stream>>>(coff, din_i, adj_in, B6, sAAi, B2, N);

  // out = 0.75 * (P1@Wsd + P2@Wds + S0@W0 + S1@W1 + S2@W2 + S3@W3 + sum b)
  k_final<<<gF, 256, 0, stream>>>(B1, B4, B7, B3, B5, B2, wb, bbv, d_out, cnt, N);
}

// Round 3
// 1183.897 us; speedup vs baseline: 2.1247x; 2.1247x over previous
//
#include <hip/hip_runtime.h>
#include <hip/hip_bf16.h>

typedef __hip_bfloat16 bf16;
typedef __bf16 bf16x8 __attribute__((ext_vector_type(8)));
typedef float f32x4 __attribute__((ext_vector_type(4)));
#define FDIM 64
#define KTOT 384
#define LDSK 392   // padded K-stride for W^T in LDS (+8 bf16 = 16B: breaks 768B stride conflicts)
#define SNIFF_THRESH 100

__device__ __forceinline__ float us2f(unsigned short u) {
  union { unsigned int i; float f; } v; v.i = ((unsigned int)u) << 16; return v.f;
}
__device__ __forceinline__ unsigned short f2bu(float v) {
  bf16 h = __float2bfloat16(v);
  return *(unsigned short*)&h;
}
__device__ __forceinline__ float inv_sqrt_pos(float d) { return d > 0.f ? rsqrtf(d) : 0.f; }

// ---------- dtype sniffing & canonicalization ----------
__global__ void k_sniff(const unsigned short* __restrict__ xs, int n, int* __restrict__ cnt) {
  int i = blockIdx.x * 256 + threadIdx.x;
  if (i < n) {
    unsigned short v = xs[i];
    if ((v & 0x7F80) == 0x7F80) atomicAdd(cnt, 1);
  }
}

__global__ void k_convert_x(const void* __restrict__ xin, bf16* __restrict__ xb,
                            const int* __restrict__ cnt, int n) {
  int i = blockIdx.x * 256 + threadIdx.x;
  if (i >= n) return;
  if (*cnt > SNIFF_THRESH) xb[i] = __float2bfloat16(((const float*)xin)[i]);
  else                     xb[i] = ((const bf16*)xin)[i];
}

// Produce W^T-concat: wt[n*384 + si*64 + kk] = W_si[kk][n], and bsum[n] = sum_si b_si[n] (fp32)
__global__ void k_convert_w(const void* W0, const void* W1, const void* W2,
                            const void* W3, const void* W4, const void* W5,
                            const void* c0, const void* c1, const void* c2,
                            const void* c3, const void* c4, const void* c5,
                            bf16* __restrict__ wt, float* __restrict__ bsum,
                            const int* __restrict__ cnt) {
  int t = blockIdx.x * 256 + threadIdx.x;
  const void* Ws[6] = {W0, W1, W2, W3, W4, W5};
  const void* Bs[6] = {c0, c1, c2, c3, c4, c5};
  bool fp = (*cnt > SNIFF_THRESH);
  if (t < 6 * 4096) {
    int si = t >> 12, o = t & 4095;
    int kk = o >> 6, n = o & 63;
    float v = fp ? ((const float*)Ws[si])[o] : __bfloat162float(((const bf16*)Ws[si])[o]);
    wt[n * KTOT + si * 64 + kk] = __float2bfloat16(v);
  } else if (t < 6 * 4096 + 64) {
    int n = t - 6 * 4096;
    float s = 0.f;
    for (int si = 0; si < 6; si++)
      s += fp ? ((const float*)Bs[si])[n] : __bfloat162float(((const bf16*)Bs[si])[n]);
    bsum[n] = s;
  }
}

// ---------- setup kernels ----------
__global__ void k_degrees(const int* __restrict__ row, const int* __restrict__ col,
                          int* __restrict__ dout, int* __restrict__ din, int E) {
  int e = blockIdx.x * 256 + threadIdx.x;
  if (e < E) {
    atomicAdd(&dout[row[e]], 1);
    atomicAdd(&din[col[e]], 1);
  }
}

__global__ void k_m4(const int* __restrict__ row, const int* __restrict__ col,
                     const int* __restrict__ dout, const int* __restrict__ din,
                     float* __restrict__ mAAt, float* __restrict__ mAtA,
                     float* __restrict__ mAAo, float* __restrict__ mAAi, int E) {
  int e = blockIdx.x * 256 + threadIdx.x;
  if (e < E) {
    int r = row[e], c = col[e];
    atomicAdd(&mAAt[r], (float)din[c]);   // Av(d_in)
    atomicAdd(&mAtA[c], (float)dout[r]);  // Atv(d_out)
    atomicAdd(&mAAo[r], (float)dout[c]);  // Av(d_out)
    atomicAdd(&mAAi[c], (float)din[r]);   // Atv(d_in)
  }
}

__global__ void k_scan_block(const int* __restrict__ in, int* __restrict__ out,
                             int* __restrict__ part, int n) {
  __shared__ int sm[256];
  int tid = threadIdx.x;
  int i = blockIdx.x * 256 + tid;
  int v = (i < n) ? in[i] : 0;
  sm[tid] = v;
  __syncthreads();
  for (int d = 1; d < 256; d <<= 1) {
    int t = (tid >= d) ? sm[tid - d] : 0;
    __syncthreads();
    if (tid >= d) sm[tid] += t;
    __syncthreads();
  }
  if (i < n) out[i] = sm[tid] - v;
  if (tid == 255) part[blockIdx.x] = sm[255];
}

__global__ void k_scan_part(int* part, int nb) {
  __shared__ int sm[1024];
  int tid = threadIdx.x;
  int v = (tid < nb) ? part[tid] : 0;
  sm[tid] = v;
  __syncthreads();
  for (int d = 1; d < 1024; d <<= 1) {
    int t = (tid >= d) ? sm[tid - d] : 0;
    __syncthreads();
    if (tid >= d) sm[tid] += t;
    __syncthreads();
  }
  if (tid < nb) part[tid] = sm[tid] - v;
}

__global__ void k_scan_add(int* __restrict__ out, const int* __restrict__ part, int n) {
  int i = blockIdx.x * 256 + threadIdx.x;
  if (i < n) out[i] += part[blockIdx.x];
}

__global__ void k_scales(const int* __restrict__ dout, const int* __restrict__ din,
                         const float* __restrict__ mAAt, const float* __restrict__ mAtA,
                         const float* __restrict__ mAAo, const float* __restrict__ mAAi,
                         float* iso, float* isi, float* sAAt, float* sAtA,
                         float* sAAo, float* sAAi, int n) {
  int i = blockIdx.x * 256 + threadIdx.x;
  if (i < n) {
    iso[i]  = inv_sqrt_pos((float)dout[i]);
    isi[i]  = inv_sqrt_pos((float)din[i]);
    sAAt[i] = inv_sqrt_pos(mAAt[i]);
    sAtA[i] = inv_sqrt_pos(mAtA[i]);
    sAAo[i] = inv_sqrt_pos(mAAo[i]);
    sAAi[i] = inv_sqrt_pos(mAAi[i]);
  }
}

__global__ void k_scatter(const int* __restrict__ row, const int* __restrict__ col,
                          const int* __restrict__ roff, const int* __restrict__ coff,
                          int* rcur, int* ccur,
                          int* __restrict__ adj_out, int* __restrict__ adj_in, int E) {
  int e = blockIdx.x * 256 + threadIdx.x;
  if (e < E) {
    int r = row[e], c = col[e];
    int p = atomicAdd(&rcur[r], 1);
    adj_out[roff[r] + p] = c;
    int q = atomicAdd(&ccur[c], 1);
    adj_in[coff[c] + q] = r;
  }
}

// ---------- SpMM gather passes ----------
// One wave per node. 4 edge subgroups (q = lane>>4) x 16 feature quads (t = lane&15).
// Each lane loads ushort4 (4 bf16 = 8B). Cross-q reduce via shfl_xor(16/32) at the end.

// 3 scaled sums of x: a_i = sum_nb s_i[nb]*x[nb].  outA (*wsA, stride 384), outB (stride 384),
// outC (stride 64).
__global__ __launch_bounds__(256)
void k_pass3(const int* __restrict__ off, const int* __restrict__ deg,
             const int* __restrict__ adj, const bf16* __restrict__ x,
             const float* __restrict__ s0, const float* __restrict__ s1,
             const float* __restrict__ s2, const float* __restrict__ wsA,
             bf16* __restrict__ outA, bf16* __restrict__ outB, bf16* __restrict__ outC,
             int N) {
  int wid = (blockIdx.x * 256 + threadIdx.x) >> 6;
  if (wid >= N) return;
  int lane = threadIdx.x & 63;
  int q = lane >> 4, t4 = (lane & 15) << 2;
  int o = off[wid], d = deg[wid];
  float a0[4] = {0,0,0,0}, a1[4] = {0,0,0,0}, a2[4] = {0,0,0,0};
  for (int e = q; e < d; e += 4) {
    int nb = adj[o + e];
    ushort4 r = *(const ushort4*)(x + (size_t)nb * FDIM + t4);
    float f0 = us2f(r.x), f1 = us2f(r.y), f2 = us2f(r.z), f3 = us2f(r.w);
    float w0 = s0[nb], w1 = s1[nb], w2 = s2[nb];
    a0[0] += w0 * f0; a0[1] += w0 * f1; a0[2] += w0 * f2; a0[3] += w0 * f3;
    a1[0] += w1 * f0; a1[1] += w1 * f1; a1[2] += w1 * f2; a1[3] += w1 * f3;
    a2[0] += w2 * f0; a2[1] += w2 * f1; a2[2] += w2 * f2; a2[3] += w2 * f3;
  }
  #pragma unroll
  for (int i = 0; i < 4; i++) {
    a0[i] += __shfl_xor(a0[i], 16); a0[i] += __shfl_xor(a0[i], 32);
    a1[i] += __shfl_xor(a1[i], 16); a1[i] += __shfl_xor(a1[i], 32);
    a2[i] += __shfl_xor(a2[i], 16); a2[i] += __shfl_xor(a2[i], 32);
  }
  if (q == 0) {
    float wA = wsA[wid];
    ushort4 uA, uB, uC;
    uA.x = f2bu(a0[0]*wA); uA.y = f2bu(a0[1]*wA); uA.z = f2bu(a0[2]*wA); uA.w = f2bu(a0[3]*wA);
    uB.x = f2bu(a1[0]);    uB.y = f2bu(a1[1]);    uB.z = f2bu(a1[2]);    uB.w = f2bu(a1[3]);
    uC.x = f2bu(a2[0]);    uC.y = f2bu(a2[1]);    uC.z = f2bu(a2[2]);    uC.w = f2bu(a2[3]);
    *(ushort4*)(outA + (size_t)wid * KTOT + t4) = uA;
    *(ushort4*)(outB + (size_t)wid * KTOT + t4) = uB;
    *(ushort4*)(outC + (size_t)wid * FDIM + t4) = uC;
  }
}

// 2 plain sums: out{A,B} = ws{A,B}[n] * sum_nb in{A,B}[nb].  Inputs strideIn; outputs stride 384.
__global__ __launch_bounds__(256)
void k_pass2(const int* __restrict__ off, const int* __restrict__ deg,
             const int* __restrict__ adj,
             const bf16* __restrict__ inA, const bf16* __restrict__ inB, int strideIn,
             const float* __restrict__ wsA, const float* __restrict__ wsB,
             bf16* __restrict__ outA, bf16* __restrict__ outB, int N) {
  int wid = (blockIdx.x * 256 + threadIdx.x) >> 6;
  if (wid >= N) return;
  int lane = threadIdx.x & 63;
  int q = lane >> 4, t4 = (lane & 15) << 2;
  int o = off[wid], d = deg[wid];
  float a0[4] = {0,0,0,0}, a1[4] = {0,0,0,0};
  for (int e = q; e < d; e += 4) {
    int nb = adj[o + e];
    ushort4 rA = *(const ushort4*)(inA + (size_t)nb * strideIn + t4);
    ushort4 rB = *(const ushort4*)(inB + (size_t)nb * strideIn + t4);
    a0[0] += us2f(rA.x); a0[1] += us2f(rA.y); a0[2] += us2f(rA.z); a0[3] += us2f(rA.w);
    a1[0] += us2f(rB.x); a1[1] += us2f(rB.y); a1[2] += us2f(rB.z); a1[3] += us2f(rB.w);
  }
  #pragma unroll
  for (int i = 0; i < 4; i++) {
    a0[i] += __shfl_xor(a0[i], 16); a0[i] += __shfl_xor(a0[i], 32);
    a1[i] += __shfl_xor(a1[i], 16); a1[i] += __shfl_xor(a1[i], 32);
  }
  if (q == 0) {
    float wA = wsA[wid], wB = wsB[wid];
    ushort4 uA, uB;
    uA.x = f2bu(a0[0]*wA); uA.y = f2bu(a0[1]*wA); uA.z = f2bu(a0[2]*wA); uA.w = f2bu(a0[3]*wA);
    uB.x = f2bu(a1[0]*wB); uB.y = f2bu(a1[1]*wB); uB.z = f2bu(a1[2]*wB); uB.w = f2bu(a1[3]*wB);
    *(ushort4*)(outA + (size_t)wid * KTOT + t4) = uA;
    *(ushort4*)(outB + (size_t)wid * KTOT + t4) = uB;
  }
}

// ---------- final MFMA GEMM: out[N,64] = 0.75*(H[N,384] @ Wcat[384,64] + bsum) ----------
// Block: 4 waves, 64 rows (16/wave). W^T staged in LDS with padded stride LDSK.
// A-frag: m = lane&15, k = (lane>>4)*8 + j  (16B contiguous from H row)
// B-frag: n = lane&15, k = (lane>>4)*8 + j  (16B ds_read from W^T row)
// C/D:    col = lane&15, row = (lane>>4)*4 + reg
__global__ __launch_bounds__(256)
void k_final(const bf16* __restrict__ H, const bf16* __restrict__ wt,
             const float* __restrict__ bsum, void* __restrict__ outv,
             const int* __restrict__ cnt, int N) {
  __shared__ bf16 Wl[64 * LDSK];
  {
    const unsigned int* wtu = (const unsigned int*)wt;
    unsigned int* wlu = (unsigned int*)Wl;
    for (int i = threadIdx.x; i < 64 * (KTOT / 2); i += 256) {
      int n = i / (KTOT / 2), k2 = i % (KTOT / 2);
      wlu[n * (LDSK / 2) + k2] = wtu[i];
    }
  }
  __syncthreads();

  int wave = threadIdx.x >> 6, lane = threadIdx.x & 63;
  int m0 = blockIdx.x * 64 + wave * 16;
  int ml = lane & 15, kq = lane >> 4;
  const bf16* Hrow = H + (size_t)(m0 + ml) * KTOT + kq * 8;

  f32x4 acc[4] = {{0,0,0,0},{0,0,0,0},{0,0,0,0},{0,0,0,0}};
  #pragma unroll
  for (int kb = 0; kb < KTOT / 32; kb++) {
    bf16x8 a = *(const bf16x8*)(Hrow + kb * 32);
    #pragma unroll
    for (int ct = 0; ct < 4; ct++) {
      bf16x8 b = *(const bf16x8*)(Wl + (size_t)(ct * 16 + ml) * LDSK + kb * 32 + kq * 8);
      acc[ct] = __builtin_amdgcn_mfma_f32_16x16x32_bf16(a, b, acc[ct], 0, 0, 0);
    }
  }

  bool fp = (*cnt > SNIFF_THRESH);
  #pragma unroll
  for (int ct = 0; ct < 4; ct++) {
    int col = ct * 16 + ml;
    float bias = bsum[col];
    #pragma unroll
    for (int r = 0; r < 4; r++) {
      int m = m0 + kq * 4 + r;
      if (m < N) {
        float val = 0.75f * (acc[ct][r] + bias);
        if (fp) ((float*)outv)[(size_t)m * FDIM + col] = val;
        else    ((bf16*)outv)[(size_t)m * FDIM + col] = __float2bfloat16(val);
      }
    }
  }
}

// ---------- host ----------
extern "C" void kernel_launch(void* const* d_in, const int* in_sizes, int n_in,
                              void* d_out, int out_size, void* d_ws, size_t ws_size,
                              hipStream_t stream) {
  const void* x = d_in[0];
  const int* ei = (const int*)d_in[1];
  int NX = in_sizes[0];
  int N = NX / FDIM;
  int E = in_sizes[1] / 2;
  const int* row = ei;
  const int* col = ei + E;

  char* p = (char*)d_ws;
  auto alloc = [&](size_t bytes) {
    bytes = (bytes + 255) & ~(size_t)255;
    char* r = p; p += bytes; return r;
  };

  // zero-init region (contiguous from d_ws start)
  int*   cnt    = (int*)alloc(4);
  int*   dout_i = (int*)alloc((size_t)N * 4);
  int*   din_i  = (int*)alloc((size_t)N * 4);
  int*   rcur   = (int*)alloc((size_t)N * 4);
  int*   ccur   = (int*)alloc((size_t)N * 4);
  float* mAAt   = (float*)alloc((size_t)N * 4);
  float* mAtA   = (float*)alloc((size_t)N * 4);
  float* mAAo   = (float*)alloc((size_t)N * 4);
  float* mAAi   = (float*)alloc((size_t)N * 4);
  size_t zbytes = (size_t)(p - (char*)d_ws);

  int* roff  = (int*)alloc((size_t)N * 4);
  int* coff  = (int*)alloc((size_t)N * 4);
  int* partA = (int*)alloc(1024 * 4);
  int* partB = (int*)alloc(1024 * 4);
  float* iso  = (float*)alloc((size_t)N * 4);
  float* isi  = (float*)alloc((size_t)N * 4);
  float* sAAt = (float*)alloc((size_t)N * 4);
  float* sAtA = (float*)alloc((size_t)N * 4);
  float* sAAo = (float*)alloc((size_t)N * 4);
  float* sAAi = (float*)alloc((size_t)N * 4);
  int* adj_out = (int*)alloc((size_t)E * 4);
  int* adj_in  = (int*)alloc((size_t)E * 4);
  bf16* xb   = (bf16*)alloc((size_t)NX * 2);
  bf16* wt   = (bf16*)alloc((size_t)6 * 4096 * 2);
  float* bsum = (float*)alloc(64 * 4);
  bf16* H  = (bf16*)alloc((size_t)N * KTOT * 2);  // 6 concatenated 64-col slots
  bf16* TQ = (bf16*)alloc((size_t)N * FDIM * 2);  // Q2 = Av(sAtA*x)
  bf16* TR = (bf16*)alloc((size_t)N * FDIM * 2);  // R2 = Atv(sAAo*x)

  hipMemsetAsync(d_ws, 0, zbytes, stream);

  int gX = (NX + 255) / 256;
  int gE = (E + 255) / 256;
  int gN = (N + 255) / 256;
  int gW = (N + 3) / 4;      // wave-per-node kernels: 4 waves/block
  int gF = (N + 63) / 64;    // final MFMA: 64 rows/block

  // dtype canonicalization
  k_sniff<<<gX, 256, 0, stream>>>((const unsigned short*)x, NX, cnt);
  k_convert_x<<<gX, 256, 0, stream>>>(x, xb, cnt, NX);
  k_convert_w<<<98, 256, 0, stream>>>(d_in[2], d_in[4], d_in[6], d_in[8], d_in[10], d_in[12],
                                      d_in[3], d_in[5], d_in[7], d_in[9], d_in[11], d_in[13],
                                      wt, bsum, cnt);

  // degrees, CSR build, scales
  k_degrees<<<gE, 256, 0, stream>>>(row, col, dout_i, din_i, E);
  k_m4<<<gE, 256, 0, stream>>>(row, col, dout_i, din_i, mAAt, mAtA, mAAo, mAAi, E);
  k_scan_block<<<gN, 256, 0, stream>>>(dout_i, roff, partA, N);
  k_scan_part<<<1, 1024, 0, stream>>>(partA, gN);
  k_scan_add<<<gN, 256, 0, stream>>>(roff, partA, N);
  k_scan_block<<<gN, 256, 0, stream>>>(din_i, coff, partB, N);
  k_scan_part<<<1, 1024, 0, stream>>>(partB, gN);
  k_scan_add<<<gN, 256, 0, stream>>>(coff, partB, N);
  k_scales<<<gN, 256, 0, stream>>>(dout_i, din_i, mAAt, mAtA, mAAo, mAAi,
                                   iso, isi, sAAt, sAtA, sAAo, sAAi, N);
  k_scatter<<<gE, 256, 0, stream>>>(row, col, roff, coff, rcur, ccur, adj_out, adj_in, E);

  // H slots: 0=P1, 1=P2, 2=S0(AAt), 3=Q1->S1(AtA), 4=S2(AA), 5=R1->S3(AtAt)
  // Pass A (Av, out-CSR): P1=iso*Av(isi*x)->slot0, R1=Av(sAAi*x)->slot5, Q2=Av(sAtA*x)->TQ
  k_pass3<<<gW, 256, 0, stream>>>(roff, dout_i, adj_out, xb, isi, sAAi, sAtA, iso,
                                  H + 0 * 64, H + 5 * 64, TQ, N);
  // Pass B (Atv, in-CSR): P2=isi*Atv(iso*x)->slot1, Q1=Atv(sAAt*x)->slot3, R2=Atv(sAAo*x)->TR
  k_pass3<<<gW, 256, 0, stream>>>(coff, din_i, adj_in, xb, iso, sAAt, sAAo, isi,
                                  H + 1 * 64, H + 3 * 64, TR, N);
  // Pass C (Av, out-CSR): S0=sAAt*Av(Q1@slot3)->slot2, S2=sAAo*Av(R1@slot5)->slot4
  k_pass2<<<gW, 256, 0, stream>>>(roff, dout_i, adj_out, H + 3 * 64, H + 5 * 64, KTOT,
                                  sAAt, sAAo, H + 2 * 64, H + 4 * 64, N);
  // Pass D (Atv, in-CSR): S1=sAtA*Atv(Q2=TQ)->slot3, S3=sAAi*Atv(R2=TR)->slot5
  k_pass2<<<gW, 256, 0, stream>>>(coff, din_i, adj_in, TQ, TR, FDIM,
                                  sAtA, sAAi, H + 3 * 64, H + 5 * 64, N);

  // out = 0.75 * (H @ Wcat + bsum)
  k_final<<<gF, 256, 0, stream>>>(H, wt, bsum, d_out, cnt, N);
}

// Round 4
// 912.687 us; speedup vs baseline: 2.7560x; 1.2972x over previous
//
#include <hip/hip_runtime.h>
#include <hip/hip_bf16.h>

typedef __hip_bfloat16 bf16;
typedef __bf16 bf16x8 __attribute__((ext_vector_type(8)));
typedef float f32x4 __attribute__((ext_vector_type(4)));
#define FDIM 64
#define KTOT 384
#define LDSK 392   // padded K-stride for W^T in LDS
#define SNIFF_THRESH 100

__device__ __forceinline__ float us2f(unsigned short u) {
  union { unsigned int i; float f; } v; v.i = ((unsigned int)u) << 16; return v.f;
}
__device__ __forceinline__ unsigned short f2bu(float v) {
  bf16 h = __float2bfloat16(v);
  return *(unsigned short*)&h;
}
__device__ __forceinline__ float inv_sqrt_pos(float d) { return d > 0.f ? rsqrtf(d) : 0.f; }

// ---------- dtype sniffing & canonicalization ----------
__global__ void k_sniff(const unsigned short* __restrict__ xs, int n, int* __restrict__ cnt) {
  int i = blockIdx.x * 256 + threadIdx.x;
  if (i < n) {
    unsigned short v = xs[i];
    if ((v & 0x7F80) == 0x7F80) atomicAdd(cnt, 1);
  }
}

__global__ void k_convert_x(const void* __restrict__ xin, bf16* __restrict__ xb,
                            const int* __restrict__ cnt, int n) {
  int i = blockIdx.x * 256 + threadIdx.x;
  if (i >= n) return;
  if (*cnt > SNIFF_THRESH) xb[i] = __float2bfloat16(((const float*)xin)[i]);
  else                     xb[i] = ((const bf16*)xin)[i];
}

// W^T-concat: wt[n*384 + si*64 + kk] = W_si[kk][n]; bsum[n] = sum_si b_si[n] (fp32)
__global__ void k_convert_w(const void* W0, const void* W1, const void* W2,
                            const void* W3, const void* W4, const void* W5,
                            const void* c0, const void* c1, const void* c2,
                            const void* c3, const void* c4, const void* c5,
                            bf16* __restrict__ wt, float* __restrict__ bsum,
                            const int* __restrict__ cnt) {
  int t = blockIdx.x * 256 + threadIdx.x;
  const void* Ws[6] = {W0, W1, W2, W3, W4, W5};
  const void* Bs[6] = {c0, c1, c2, c3, c4, c5};
  bool fp = (*cnt > SNIFF_THRESH);
  if (t < 6 * 4096) {
    int si = t >> 12, o = t & 4095;
    int kk = o >> 6, n = o & 63;
    float v = fp ? ((const float*)Ws[si])[o] : __bfloat162float(((const bf16*)Ws[si])[o]);
    wt[n * KTOT + si * 64 + kk] = __float2bfloat16(v);
  } else if (t < 6 * 4096 + 64) {
    int n = t - 6 * 4096;
    float s = 0.f;
    for (int si = 0; si < 6; si++)
      s += fp ? ((const float*)Bs[si])[n] : __bfloat162float(((const bf16*)Bs[si])[n]);
    bsum[n] = s;
  }
}

// ---------- setup kernels ----------
__global__ void k_degrees(const int* __restrict__ row, const int* __restrict__ col,
                          int* __restrict__ dout, int* __restrict__ din, int E) {
  int e = blockIdx.x * 256 + threadIdx.x;
  if (e < E) {
    atomicAdd(&dout[row[e]], 1);
    atomicAdd(&din[col[e]], 1);
  }
}

__global__ void k_scan_block(const int* __restrict__ in, int* __restrict__ out,
                             int* __restrict__ part, int n) {
  __shared__ int sm[256];
  int tid = threadIdx.x;
  int i = blockIdx.x * 256 + tid;
  int v = (i < n) ? in[i] : 0;
  sm[tid] = v;
  __syncthreads();
  for (int d = 1; d < 256; d <<= 1) {
    int t = (tid >= d) ? sm[tid - d] : 0;
    __syncthreads();
    if (tid >= d) sm[tid] += t;
    __syncthreads();
  }
  if (i < n) out[i] = sm[tid] - v;
  if (tid == 255) part[blockIdx.x] = sm[255];
}

__global__ void k_scan_part(int* part, int nb) {
  __shared__ int sm[1024];
  int tid = threadIdx.x;
  int v = (tid < nb) ? part[tid] : 0;
  sm[tid] = v;
  __syncthreads();
  for (int d = 1; d < 1024; d <<= 1) {
    int t = (tid >= d) ? sm[tid - d] : 0;
    __syncthreads();
    if (tid >= d) sm[tid] += t;
    __syncthreads();
  }
  if (tid < nb) part[tid] = sm[tid] - v;
}

__global__ void k_scan_add(int* __restrict__ out, const int* __restrict__ part, int n) {
  int i = blockIdx.x * 256 + threadIdx.x;
  if (i < n) out[i] += part[blockIdx.x];
}

__global__ void k_scatter(const int* __restrict__ row, const int* __restrict__ col,
                          const int* __restrict__ roff, const int* __restrict__ coff,
                          int* rcur, int* ccur,
                          int* __restrict__ adj_out, int* __restrict__ adj_in, int E) {
  int e = blockIdx.x * 256 + threadIdx.x;
  if (e < E) {
    int r = row[e], c = col[e];
    int p = atomicAdd(&rcur[r], 1);
    adj_out[roff[r] + p] = c;
    int q = atomicAdd(&ccur[c], 1);
    adj_in[coff[c] + q] = r;
  }
}

// Second-order degree sums as CSR gathers (no atomics) + all 6 inv-sqrt scales.
__global__ __launch_bounds__(256)
void k_m4scales(const int* __restrict__ roff, const int* __restrict__ coff,
                const int* __restrict__ dout, const int* __restrict__ din,
                const int* __restrict__ adj_out, const int* __restrict__ adj_in,
                float* __restrict__ iso, float* __restrict__ isi,
                float* __restrict__ sAAt, float* __restrict__ sAtA,
                float* __restrict__ sAAo, float* __restrict__ sAAi, int N) {
  int n = blockIdx.x * 256 + threadIdx.x;
  if (n >= N) return;
  int dn = dout[n], cn = din[n];
  int o0 = roff[n];
  float aat = 0.f, aao = 0.f;
  for (int e = 0; e < dn; e++) {
    int c = adj_out[o0 + e];
    aat += (float)din[c];   // Av(d_in)
    aao += (float)dout[c];  // Av(d_out)
  }
  int i0 = coff[n];
  float ata = 0.f, aai = 0.f;
  for (int e = 0; e < cn; e++) {
    int r = adj_in[i0 + e];
    ata += (float)dout[r];  // Atv(d_out)
    aai += (float)din[r];   // Atv(d_in)
  }
  iso[n]  = inv_sqrt_pos((float)dn);
  isi[n]  = inv_sqrt_pos((float)cn);
  sAAt[n] = inv_sqrt_pos(aat);
  sAtA[n] = inv_sqrt_pos(ata);
  sAAo[n] = inv_sqrt_pos(aao);
  sAAi[n] = inv_sqrt_pos(aai);
}

// ---------- SpMM gather passes ----------
// One wave per node. 4 edge subgroups (q=lane>>4) x 16 feature quads. ushort4 loads.
__global__ __launch_bounds__(256)
void k_pass3(const int* __restrict__ off, const int* __restrict__ deg,
             const int* __restrict__ adj, const bf16* __restrict__ x,
             const float* __restrict__ s0, const float* __restrict__ s1,
             const float* __restrict__ s2, const float* __restrict__ wsA,
             bf16* __restrict__ outA, bf16* __restrict__ outB, bf16* __restrict__ outC,
             int N) {
  int wid = (blockIdx.x * 256 + threadIdx.x) >> 6;
  if (wid >= N) return;
  int lane = threadIdx.x & 63;
  int q = lane >> 4, t4 = (lane & 15) << 2;
  int o = off[wid], d = deg[wid];
  float a0[4] = {0,0,0,0}, a1[4] = {0,0,0,0}, a2[4] = {0,0,0,0};
  for (int e = q; e < d; e += 4) {
    int nb = adj[o + e];
    ushort4 r = *(const ushort4*)(x + (size_t)nb * FDIM + t4);
    float f0 = us2f(r.x), f1 = us2f(r.y), f2 = us2f(r.z), f3 = us2f(r.w);
    float w0 = s0[nb], w1 = s1[nb], w2 = s2[nb];
    a0[0] += w0 * f0; a0[1] += w0 * f1; a0[2] += w0 * f2; a0[3] += w0 * f3;
    a1[0] += w1 * f0; a1[1] += w1 * f1; a1[2] += w1 * f2; a1[3] += w1 * f3;
    a2[0] += w2 * f0; a2[1] += w2 * f1; a2[2] += w2 * f2; a2[3] += w2 * f3;
  }
  #pragma unroll
  for (int i = 0; i < 4; i++) {
    a0[i] += __shfl_xor(a0[i], 16); a0[i] += __shfl_xor(a0[i], 32);
    a1[i] += __shfl_xor(a1[i], 16); a1[i] += __shfl_xor(a1[i], 32);
    a2[i] += __shfl_xor(a2[i], 16); a2[i] += __shfl_xor(a2[i], 32);
  }
  if (q == 0) {
    float wA = wsA[wid];
    ushort4 uA, uB, uC;
    uA.x = f2bu(a0[0]*wA); uA.y = f2bu(a0[1]*wA); uA.z = f2bu(a0[2]*wA); uA.w = f2bu(a0[3]*wA);
    uB.x = f2bu(a1[0]);    uB.y = f2bu(a1[1]);    uB.z = f2bu(a1[2]);    uB.w = f2bu(a1[3]);
    uC.x = f2bu(a2[0]);    uC.y = f2bu(a2[1]);    uC.z = f2bu(a2[2]);    uC.w = f2bu(a2[3]);
    *(ushort4*)(outA + (size_t)wid * KTOT + t4) = uA;
    *(ushort4*)(outB + (size_t)wid * KTOT + t4) = uB;
    *(ushort4*)(outC + (size_t)wid * FDIM + t4) = uC;
  }
}

__global__ __launch_bounds__(256)
void k_pass2(const int* __restrict__ off, const int* __restrict__ deg,
             const int* __restrict__ adj,
             const bf16* __restrict__ inA, const bf16* __restrict__ inB, int strideIn,
             const float* __restrict__ wsA, const float* __restrict__ wsB,
             bf16* __restrict__ outA, bf16* __restrict__ outB, int N) {
  int wid = (blockIdx.x * 256 + threadIdx.x) >> 6;
  if (wid >= N) return;
  int lane = threadIdx.x & 63;
  int q = lane >> 4, t4 = (lane & 15) << 2;
  int o = off[wid], d = deg[wid];
  float a0[4] = {0,0,0,0}, a1[4] = {0,0,0,0};
  for (int e = q; e < d; e += 4) {
    int nb = adj[o + e];
    ushort4 rA = *(const ushort4*)(inA + (size_t)nb * strideIn + t4);
    ushort4 rB = *(const ushort4*)(inB + (size_t)nb * strideIn + t4);
    a0[0] += us2f(rA.x); a0[1] += us2f(rA.y); a0[2] += us2f(rA.z); a0[3] += us2f(rA.w);
    a1[0] += us2f(rB.x); a1[1] += us2f(rB.y); a1[2] += us2f(rB.z); a1[3] += us2f(rB.w);
  }
  #pragma unroll
  for (int i = 0; i < 4; i++) {
    a0[i] += __shfl_xor(a0[i], 16); a0[i] += __shfl_xor(a0[i], 32);
    a1[i] += __shfl_xor(a1[i], 16); a1[i] += __shfl_xor(a1[i], 32);
  }
  if (q == 0) {
    float wA = wsA[wid], wB = wsB[wid];
    ushort4 uA, uB;
    uA.x = f2bu(a0[0]*wA); uA.y = f2bu(a0[1]*wA); uA.z = f2bu(a0[2]*wA); uA.w = f2bu(a0[3]*wA);
    uB.x = f2bu(a1[0]*wB); uB.y = f2bu(a1[1]*wB); uB.z = f2bu(a1[2]*wB); uB.w = f2bu(a1[3]*wB);
    *(ushort4*)(outA + (size_t)wid * KTOT + t4) = uA;
    *(ushort4*)(outB + (size_t)wid * KTOT + t4) = uB;
  }
}

// ---------- final MFMA GEMM: out[N,64] = 0.75*(H[N,384] @ Wcat[384,64] + bsum) ----------
__global__ __launch_bounds__(256)
void k_final(const bf16* __restrict__ H, const bf16* __restrict__ wt,
             const float* __restrict__ bsum, void* __restrict__ outv,
             const int* __restrict__ cnt, int N) {
  __shared__ bf16 Wl[64 * LDSK];
  {
    const unsigned int* wtu = (const unsigned int*)wt;
    unsigned int* wlu = (unsigned int*)Wl;
    for (int i = threadIdx.x; i < 64 * (KTOT / 2); i += 256) {
      int n = i / (KTOT / 2), k2 = i % (KTOT / 2);
      wlu[n * (LDSK / 2) + k2] = wtu[i];
    }
  }
  __syncthreads();

  int wave = threadIdx.x >> 6, lane = threadIdx.x & 63;
  int m0 = blockIdx.x * 64 + wave * 16;
  int ml = lane & 15, kq = lane >> 4;
  const bf16* Hrow = H + (size_t)(m0 + ml) * KTOT + kq * 8;

  f32x4 acc[4] = {{0,0,0,0},{0,0,0,0},{0,0,0,0},{0,0,0,0}};
  #pragma unroll
  for (int kb = 0; kb < KTOT / 32; kb++) {
    bf16x8 a = *(const bf16x8*)(Hrow + kb * 32);
    #pragma unroll
    for (int ct = 0; ct < 4; ct++) {
      bf16x8 b = *(const bf16x8*)(Wl + (size_t)(ct * 16 + ml) * LDSK + kb * 32 + kq * 8);
      acc[ct] = __builtin_amdgcn_mfma_f32_16x16x32_bf16(a, b, acc[ct], 0, 0, 0);
    }
  }

  bool fp = (*cnt > SNIFF_THRESH);
  #pragma unroll
  for (int ct = 0; ct < 4; ct++) {
    int col = ct * 16 + ml;
    float bias = bsum[col];
    #pragma unroll
    for (int r = 0; r < 4; r++) {
      int m = m0 + kq * 4 + r;
      if (m < N) {
        float val = 0.75f * (acc[ct][r] + bias);
        if (fp) ((float*)outv)[(size_t)m * FDIM + col] = val;
        else    ((bf16*)outv)[(size_t)m * FDIM + col] = __float2bfloat16(val);
      }
    }
  }
}

// ---------- host ----------
extern "C" void kernel_launch(void* const* d_in, const int* in_sizes, int n_in,
                              void* d_out, int out_size, void* d_ws, size_t ws_size,
                              hipStream_t stream) {
  const void* x = d_in[0];
  const int* ei = (const int*)d_in[1];
  int NX = in_sizes[0];
  int N = NX / FDIM;
  int E = in_sizes[1] / 2;
  const int* row = ei;
  const int* col = ei + E;

  char* p = (char*)d_ws;
  auto alloc = [&](size_t bytes) {
    bytes = (bytes + 255) & ~(size_t)255;
    char* r = p; p += bytes; return r;
  };

  // zero-init region (contiguous from d_ws start)
  int*   cnt    = (int*)alloc(4);
  int*   dout_i = (int*)alloc((size_t)N * 4);
  int*   din_i  = (int*)alloc((size_t)N * 4);
  int*   rcur   = (int*)alloc((size_t)N * 4);
  int*   ccur   = (int*)alloc((size_t)N * 4);
  size_t zbytes = (size_t)(p - (char*)d_ws);

  int* roff  = (int*)alloc((size_t)N * 4);
  int* coff  = (int*)alloc((size_t)N * 4);
  int* partA = (int*)alloc(1024 * 4);
  int* partB = (int*)alloc(1024 * 4);
  float* iso  = (float*)alloc((size_t)N * 4);
  float* isi  = (float*)alloc((size_t)N * 4);
  float* sAAt = (float*)alloc((size_t)N * 4);
  float* sAtA = (float*)alloc((size_t)N * 4);
  float* sAAo = (float*)alloc((size_t)N * 4);
  float* sAAi = (float*)alloc((size_t)N * 4);
  int* adj_out = (int*)alloc((size_t)E * 4);
  int* adj_in  = (int*)alloc((size_t)E * 4);
  bf16* xb   = (bf16*)alloc((size_t)NX * 2);
  bf16* wt   = (bf16*)alloc((size_t)6 * 4096 * 2);
  float* bsum = (float*)alloc(64 * 4);
  bf16* H  = (bf16*)alloc((size_t)N * KTOT * 2);  // 6 concatenated 64-col slots
  bf16* TQ = (bf16*)alloc((size_t)N * FDIM * 2);  // Q2 = Av(sAtA*x)
  bf16* TR = (bf16*)alloc((size_t)N * FDIM * 2);  // R2 = Atv(sAAo*x)

  hipMemsetAsync(d_ws, 0, zbytes, stream);

  int gX = (NX + 255) / 256;
  int gE = (E + 255) / 256;
  int gN = (N + 255) / 256;
  int gW = (N + 3) / 4;      // wave-per-node kernels
  int gF = (N + 63) / 64;    // final MFMA

  // dtype canonicalization
  k_sniff<<<gX, 256, 0, stream>>>((const unsigned short*)x, NX, cnt);
  k_convert_x<<<gX, 256, 0, stream>>>(x, xb, cnt, NX);
  k_convert_w<<<98, 256, 0, stream>>>(d_in[2], d_in[4], d_in[6], d_in[8], d_in[10], d_in[12],
                                      d_in[3], d_in[5], d_in[7], d_in[9], d_in[11], d_in[13],
                                      wt, bsum, cnt);

  // degrees, CSR build, fused second-order sums + scales (no float atomics)
  k_degrees<<<gE, 256, 0, stream>>>(row, col, dout_i, din_i, E);
  k_scan_block<<<gN, 256, 0, stream>>>(dout_i, roff, partA, N);
  k_scan_part<<<1, 1024, 0, stream>>>(partA, gN);
  k_scan_add<<<gN, 256, 0, stream>>>(roff, partA, N);
  k_scan_block<<<gN, 256, 0, stream>>>(din_i, coff, partB, N);
  k_scan_part<<<1, 1024, 0, stream>>>(partB, gN);
  k_scan_add<<<gN, 256, 0, stream>>>(coff, partB, N);
  k_scatter<<<gE, 256, 0, stream>>>(row, col, roff, coff, rcur, ccur, adj_out, adj_in, E);
  k_m4scales<<<gN, 256, 0, stream>>>(roff, coff, dout_i, din_i, adj_out, adj_in,
                                     iso, isi, sAAt, sAtA, sAAo, sAAi, N);

  // H slots: 0=P1, 1=P2, 2=S0(AAt), 3=Q1->S1(AtA), 4=S2(AA), 5=R1->S3(AtAt)
  k_pass3<<<gW, 256, 0, stream>>>(roff, dout_i, adj_out, xb, isi, sAAi, sAtA, iso,
                                  H + 0 * 64, H + 5 * 64, TQ, N);
  k_pass3<<<gW, 256, 0, stream>>>(coff, din_i, adj_in, xb, iso, sAAt, sAAo, isi,
                                  H + 1 * 64, H + 3 * 64, TR, N);
  k_pass2<<<gW, 256, 0, stream>>>(roff, dout_i, adj_out, H + 3 * 64, H + 5 * 64, KTOT,
                                  sAAt, sAAo, H + 2 * 64, H + 4 * 64, N);
  k_pass2<<<gW, 256, 0, stream>>>(coff, din_i, adj_in, TQ, TR, FDIM,
                                  sAtA, sAAi, H + 3 * 64, H + 5 * 64, N);

  // out = 0.75 * (H @ Wcat + bsum)
  k_final<<<gF, 256, 0, stream>>>(H, wt, bsum, d_out, cnt, N);
}

// Round 5
// 698.735 us; speedup vs baseline: 3.5999x; 1.3062x over previous
//
#include <hip/hip_runtime.h>
#include <hip/hip_bf16.h>

typedef __hip_bfloat16 bf16;
typedef __bf16 bf16x8 __attribute__((ext_vector_type(8)));
typedef float f32x4 __attribute__((ext_vector_type(4)));
#define FDIM 64
#define KTOT 384
#define LDSK 392   // padded K-stride for W^T in LDS
#define SNIFF_THRESH 100
#define MAXNB 1024 // max node buckets (supports N <= 131072; here N=100K -> 782)

__device__ __forceinline__ float us2f(unsigned short u) {
  union { unsigned int i; float f; } v; v.i = ((unsigned int)u) << 16; return v.f;
}
__device__ __forceinline__ unsigned short f2bu(float v) {
  bf16 h = __float2bfloat16(v);
  return *(unsigned short*)&h;
}
__device__ __forceinline__ float inv_sqrt_pos(float d) { return d > 0.f ? rsqrtf(d) : 0.f; }

// ---------- dtype sniffing & canonicalization ----------
__global__ void k_sniff(const unsigned short* __restrict__ xs, int n, int* __restrict__ cnt) {
  int i = blockIdx.x * 256 + threadIdx.x;
  if (i < n) {
    unsigned short v = xs[i];
    if ((v & 0x7F80) == 0x7F80) atomicAdd(cnt, 1);
  }
}

__global__ void k_convert_x(const void* __restrict__ xin, bf16* __restrict__ xb,
                            const int* __restrict__ cnt, int n) {
  int i = blockIdx.x * 256 + threadIdx.x;
  if (i >= n) return;
  if (*cnt > SNIFF_THRESH) xb[i] = __float2bfloat16(((const float*)xin)[i]);
  else                     xb[i] = ((const bf16*)xin)[i];
}

// W^T-concat: wt[n*384 + si*64 + kk] = W_si[kk][n]; bsum[n] = sum_si b_si[n] (fp32)
__global__ void k_convert_w(const void* W0, const void* W1, const void* W2,
                            const void* W3, const void* W4, const void* W5,
                            const void* c0, const void* c1, const void* c2,
                            const void* c3, const void* c4, const void* c5,
                            bf16* __restrict__ wt, float* __restrict__ bsum,
                            const int* __restrict__ cnt) {
  int t = blockIdx.x * 256 + threadIdx.x;
  const void* Ws[6] = {W0, W1, W2, W3, W4, W5};
  const void* Bs[6] = {c0, c1, c2, c3, c4, c5};
  bool fp = (*cnt > SNIFF_THRESH);
  if (t < 6 * 4096) {
    int si = t >> 12, o = t & 4095;
    int kk = o >> 6, n = o & 63;
    float v = fp ? ((const float*)Ws[si])[o] : __bfloat162float(((const bf16*)Ws[si])[o]);
    wt[n * KTOT + si * 64 + kk] = __float2bfloat16(v);
  } else if (t < 6 * 4096 + 64) {
    int n = t - 6 * 4096;
    float s = 0.f;
    for (int si = 0; si < 6; si++)
      s += fp ? ((const float*)Bs[si])[n] : __bfloat162float(((const bf16*)Bs[si])[n]);
    bsum[n] = s;
  }
}

// ---------- CSR build via LDS counting sort (no global atomics) ----------
// Buckets: node >> 7 (128 nodes each). Edge blocks: 2048 edges (256 thr x 8).
// hist layout: [dir*NB + bucket][NBLK] , dir 0 = by-row (out), 1 = by-col (in).

__global__ __launch_bounds__(256)
void k_hist(const int* __restrict__ row, const int* __restrict__ col,
            int* __restrict__ hist, int E, int NB, int NBLK) {
  __shared__ int hr[MAXNB], hc[MAXNB];
  for (int i = threadIdx.x; i < NB; i += 256) { hr[i] = 0; hc[i] = 0; }
  __syncthreads();
  int base = blockIdx.x << 11;
  for (int k = 0; k < 8; k++) {
    int e = base + k * 256 + threadIdx.x;
    if (e < E) {
      atomicAdd(&hr[row[e] >> 7], 1);
      atomicAdd(&hc[col[e] >> 7], 1);
    }
  }
  __syncthreads();
  for (int i = threadIdx.x; i < NB; i += 256) {
    hist[(size_t)i * NBLK + blockIdx.x] = hr[i];
    hist[(size_t)(NB + i) * NBLK + blockIdx.x] = hc[i];
  }
}

__global__ void k_scan_block(const int* __restrict__ in, int* __restrict__ out,
                             int* __restrict__ part, int n) {
  __shared__ int sm[256];
  int tid = threadIdx.x;
  int i = blockIdx.x * 256 + tid;
  int v = (i < n) ? in[i] : 0;
  sm[tid] = v;
  __syncthreads();
  for (int d = 1; d < 256; d <<= 1) {
    int t = (tid >= d) ? sm[tid - d] : 0;
    __syncthreads();
    if (tid >= d) sm[tid] += t;
    __syncthreads();
  }
  if (i < n) out[i] = sm[tid] - v;
  if (tid == 255) part[blockIdx.x] = sm[255];
}

__global__ void k_scan_part(int* part, int nb) {
  __shared__ int sm[1024];
  int tid = threadIdx.x;
  int v = (tid < nb) ? part[tid] : 0;
  sm[tid] = v;
  __syncthreads();
  for (int d = 1; d < 1024; d <<= 1) {
    int t = (tid >= d) ? sm[tid - d] : 0;
    __syncthreads();
    if (tid >= d) sm[tid] += t;
    __syncthreads();
  }
  if (tid < nb) part[tid] = sm[tid] - v;
}

__global__ void k_scan_add(int* __restrict__ out, const int* __restrict__ part, int n) {
  int i = blockIdx.x * 256 + threadIdx.x;
  if (i < n) out[i] += part[blockIdx.x];
}

// Scatter edges into bucket-partitioned packed array: (other << 7) | local_node.
// Positions come from the scanned hist; intra-block rank via LDS atomics.
__global__ __launch_bounds__(256)
void k_bucket_scatter(const int* __restrict__ row, const int* __restrict__ col,
                      const int* __restrict__ hist, int* __restrict__ packed,
                      int E, int NB, int NBLK) {
  __shared__ int br[MAXNB], bc[MAXNB];
  for (int i = threadIdx.x; i < NB; i += 256) {
    br[i] = hist[(size_t)i * NBLK + blockIdx.x];
    bc[i] = hist[(size_t)(NB + i) * NBLK + blockIdx.x];
  }
  __syncthreads();
  int base = blockIdx.x << 11;
  for (int k = 0; k < 8; k++) {
    int e = base + k * 256 + threadIdx.x;
    if (e < E) {
      int r = row[e], c = col[e];
      int pr = atomicAdd(&br[r >> 7], 1);
      packed[pr] = (c << 7) | (r & 127);
      int pc = atomicAdd(&bc[c >> 7], 1);
      packed[pc] = (r << 7) | (c & 127);
    }
  }
}

// One block per (direction, bucket): per-node counts -> degrees, offsets, sorted adj.
__global__ __launch_bounds__(256)
void k_bucket_csr(const int* __restrict__ hist, const int* __restrict__ packed,
                  int* __restrict__ adj,
                  int* __restrict__ dout, int* __restrict__ roff,
                  int* __restrict__ din, int* __restrict__ coff,
                  int N, int NB, int NBLK, int E2) {
  __shared__ int cnt[128], scn[128], cur[128];
  int gb = blockIdx.x;            // combined bucket index in [0, 2*NB)
  int tid = threadIdx.x;
  if (tid < 128) { cnt[tid] = 0; cur[tid] = 0; }
  __syncthreads();
  int start = hist[(size_t)gb * NBLK];
  int end = (gb + 1 < gridDim.x) ? hist[(size_t)(gb + 1) * NBLK] : E2;
  for (int i = start + tid; i < end; i += 256)
    atomicAdd(&cnt[packed[i] & 127], 1);
  __syncthreads();
  if (tid == 0) {
    int a = 0;
    for (int i = 0; i < 128; i++) { scn[i] = a; a += cnt[i]; }
  }
  __syncthreads();
  if (tid < 128) {
    int b = gb < NB ? gb : gb - NB;
    int node = (b << 7) + tid;
    if (node < N) {
      if (gb < NB) { dout[node] = cnt[tid]; roff[node] = start + scn[tid]; }
      else         { din[node]  = cnt[tid]; coff[node] = start + scn[tid]; }
    }
  }
  __syncthreads();
  for (int i = start + tid; i < end; i += 256) {
    int v = packed[i];
    int l = v & 127, o = v >> 7;
    int rk = atomicAdd(&cur[l], 1);
    adj[start + scn[l] + rk] = o;
  }
}

// Second-order degree sums as CSR gathers + all 6 inv-sqrt scales.
__global__ __launch_bounds__(256)
void k_m4scales(const int* __restrict__ roff, const int* __restrict__ coff,
                const int* __restrict__ dout, const int* __restrict__ din,
                const int* __restrict__ adj,
                float* __restrict__ iso, float* __restrict__ isi,
                float* __restrict__ sAAt, float* __restrict__ sAtA,
                float* __restrict__ sAAo, float* __restrict__ sAAi, int N) {
  int n = blockIdx.x * 256 + threadIdx.x;
  if (n >= N) return;
  int dn = dout[n], cn = din[n];
  int o0 = roff[n];
  float aat = 0.f, aao = 0.f;
  for (int e = 0; e < dn; e++) {
    int c = adj[o0 + e];
    aat += (float)din[c];
    aao += (float)dout[c];
  }
  int i0 = coff[n];
  float ata = 0.f, aai = 0.f;
  for (int e = 0; e < cn; e++) {
    int r = adj[i0 + e];
    ata += (float)dout[r];
    aai += (float)din[r];
  }
  iso[n]  = inv_sqrt_pos((float)dn);
  isi[n]  = inv_sqrt_pos((float)cn);
  sAAt[n] = inv_sqrt_pos(aat);
  sAtA[n] = inv_sqrt_pos(ata);
  sAAo[n] = inv_sqrt_pos(aao);
  sAAi[n] = inv_sqrt_pos(aai);
}

// ---------- SpMM gather passes ----------
__global__ __launch_bounds__(256)
void k_pass3(const int* __restrict__ off, const int* __restrict__ deg,
             const int* __restrict__ adj, const bf16* __restrict__ x,
             const float* __restrict__ s0, const float* __restrict__ s1,
             const float* __restrict__ s2, const float* __restrict__ wsA,
             bf16* __restrict__ outA, bf16* __restrict__ outB, bf16* __restrict__ outC,
             int N) {
  int wid = (blockIdx.x * 256 + threadIdx.x) >> 6;
  if (wid >= N) return;
  int lane = threadIdx.x & 63;
  int q = lane >> 4, t4 = (lane & 15) << 2;
  int o = off[wid], d = deg[wid];
  float a0[4] = {0,0,0,0}, a1[4] = {0,0,0,0}, a2[4] = {0,0,0,0};
  for (int e = q; e < d; e += 4) {
    int nb = adj[o + e];
    ushort4 r = *(const ushort4*)(x + (size_t)nb * FDIM + t4);
    float f0 = us2f(r.x), f1 = us2f(r.y), f2 = us2f(r.z), f3 = us2f(r.w);
    float w0 = s0[nb], w1 = s1[nb], w2 = s2[nb];
    a0[0] += w0 * f0; a0[1] += w0 * f1; a0[2] += w0 * f2; a0[3] += w0 * f3;
    a1[0] += w1 * f0; a1[1] += w1 * f1; a1[2] += w1 * f2; a1[3] += w1 * f3;
    a2[0] += w2 * f0; a2[1] += w2 * f1; a2[2] += w2 * f2; a2[3] += w2 * f3;
  }
  #pragma unroll
  for (int i = 0; i < 4; i++) {
    a0[i] += __shfl_xor(a0[i], 16); a0[i] += __shfl_xor(a0[i], 32);
    a1[i] += __shfl_xor(a1[i], 16); a1[i] += __shfl_xor(a1[i], 32);
    a2[i] += __shfl_xor(a2[i], 16); a2[i] += __shfl_xor(a2[i], 32);
  }
  if (q == 0) {
    float wA = wsA[wid];
    ushort4 uA, uB, uC;
    uA.x = f2bu(a0[0]*wA); uA.y = f2bu(a0[1]*wA); uA.z = f2bu(a0[2]*wA); uA.w = f2bu(a0[3]*wA);
    uB.x = f2bu(a1[0]);    uB.y = f2bu(a1[1]);    uB.z = f2bu(a1[2]);    uB.w = f2bu(a1[3]);
    uC.x = f2bu(a2[0]);    uC.y = f2bu(a2[1]);    uC.z = f2bu(a2[2]);    uC.w = f2bu(a2[3]);
    *(ushort4*)(outA + (size_t)wid * KTOT + t4) = uA;
    *(ushort4*)(outB + (size_t)wid * KTOT + t4) = uB;
    *(ushort4*)(outC + (size_t)wid * FDIM + t4) = uC;
  }
}

__global__ __launch_bounds__(256)
void k_pass2(const int* __restrict__ off, const int* __restrict__ deg,
             const int* __restrict__ adj,
             const bf16* __restrict__ inA, const bf16* __restrict__ inB, int strideIn,
             const float* __restrict__ wsA, const float* __restrict__ wsB,
             bf16* __restrict__ outA, bf16* __restrict__ outB, int N) {
  int wid = (blockIdx.x * 256 + threadIdx.x) >> 6;
  if (wid >= N) return;
  int lane = threadIdx.x & 63;
  int q = lane >> 4, t4 = (lane & 15) << 2;
  int o = off[wid], d = deg[wid];
  float a0[4] = {0,0,0,0}, a1[4] = {0,0,0,0};
  for (int e = q; e < d; e += 4) {
    int nb = adj[o + e];
    ushort4 rA = *(const ushort4*)(inA + (size_t)nb * strideIn + t4);
    ushort4 rB = *(const ushort4*)(inB + (size_t)nb * strideIn + t4);
    a0[0] += us2f(rA.x); a0[1] += us2f(rA.y); a0[2] += us2f(rA.z); a0[3] += us2f(rA.w);
    a1[0] += us2f(rB.x); a1[1] += us2f(rB.y); a1[2] += us2f(rB.z); a1[3] += us2f(rB.w);
  }
  #pragma unroll
  for (int i = 0; i < 4; i++) {
    a0[i] += __shfl_xor(a0[i], 16); a0[i] += __shfl_xor(a0[i], 32);
    a1[i] += __shfl_xor(a1[i], 16); a1[i] += __shfl_xor(a1[i], 32);
  }
  if (q == 0) {
    float wA = wsA[wid], wB = wsB[wid];
    ushort4 uA, uB;
    uA.x = f2bu(a0[0]*wA); uA.y = f2bu(a0[1]*wA); uA.z = f2bu(a0[2]*wA); uA.w = f2bu(a0[3]*wA);
    uB.x = f2bu(a1[0]*wB); uB.y = f2bu(a1[1]*wB); uB.z = f2bu(a1[2]*wB); uB.w = f2bu(a1[3]*wB);
    *(ushort4*)(outA + (size_t)wid * KTOT + t4) = uA;
    *(ushort4*)(outB + (size_t)wid * KTOT + t4) = uB;
  }
}

// ---------- final MFMA GEMM: out[N,64] = 0.75*(H[N,384] @ Wcat[384,64] + bsum) ----------
__global__ __launch_bounds__(256)
void k_final(const bf16* __restrict__ H, const bf16* __restrict__ wt,
             const float* __restrict__ bsum, void* __restrict__ outv,
             const int* __restrict__ cnt, int N) {
  __shared__ bf16 Wl[64 * LDSK];
  {
    const unsigned int* wtu = (const unsigned int*)wt;
    unsigned int* wlu = (unsigned int*)Wl;
    for (int i = threadIdx.x; i < 64 * (KTOT / 2); i += 256) {
      int n = i / (KTOT / 2), k2 = i % (KTOT / 2);
      wlu[n * (LDSK / 2) + k2] = wtu[i];
    }
  }
  __syncthreads();

  int wave = threadIdx.x >> 6, lane = threadIdx.x & 63;
  int m0 = blockIdx.x * 64 + wave * 16;
  int ml = lane & 15, kq = lane >> 4;
  const bf16* Hrow = H + (size_t)(m0 + ml) * KTOT + kq * 8;

  f32x4 acc[4] = {{0,0,0,0},{0,0,0,0},{0,0,0,0},{0,0,0,0}};
  #pragma unroll
  for (int kb = 0; kb < KTOT / 32; kb++) {
    bf16x8 a = *(const bf16x8*)(Hrow + kb * 32);
    #pragma unroll
    for (int ct = 0; ct < 4; ct++) {
      bf16x8 b = *(const bf16x8*)(Wl + (size_t)(ct * 16 + ml) * LDSK + kb * 32 + kq * 8);
      acc[ct] = __builtin_amdgcn_mfma_f32_16x16x32_bf16(a, b, acc[ct], 0, 0, 0);
    }
  }

  bool fp = (*cnt > SNIFF_THRESH);
  #pragma unroll
  for (int ct = 0; ct < 4; ct++) {
    int col = ct * 16 + ml;
    float bias = bsum[col];
    #pragma unroll
    for (int r = 0; r < 4; r++) {
      int m = m0 + kq * 4 + r;
      if (m < N) {
        float val = 0.75f * (acc[ct][r] + bias);
        if (fp) ((float*)outv)[(size_t)m * FDIM + col] = val;
        else    ((bf16*)outv)[(size_t)m * FDIM + col] = __float2bfloat16(val);
      }
    }
  }
}

// ---------- host ----------
extern "C" void kernel_launch(void* const* d_in, const int* in_sizes, int n_in,
                              void* d_out, int out_size, void* d_ws, size_t ws_size,
                              hipStream_t stream) {
  const void* x = d_in[0];
  const int* ei = (const int*)d_in[1];
  int NX = in_sizes[0];
  int N = NX / FDIM;
  int E = in_sizes[1] / 2;
  const int* row = ei;
  const int* col = ei + E;

  char* p = (char*)d_ws;
  auto alloc = [&](size_t bytes) {
    bytes = (bytes + 255) & ~(size_t)255;
    char* r = p; p += bytes; return r;
  };

  int*   cnt    = (int*)alloc(4);          // zero-init
  int*   dout_i = (int*)alloc((size_t)N * 4);
  int*   din_i  = (int*)alloc((size_t)N * 4);
  int* roff  = (int*)alloc((size_t)N * 4);
  int* coff  = (int*)alloc((size_t)N * 4);
  int* p1    = (int*)alloc(8192 * 4);
  int* p2    = (int*)alloc(1024 * 4);
  float* iso  = (float*)alloc((size_t)N * 4);
  float* isi  = (float*)alloc((size_t)N * 4);
  float* sAAt = (float*)alloc((size_t)N * 4);
  float* sAtA = (float*)alloc((size_t)N * 4);
  float* sAAo = (float*)alloc((size_t)N * 4);
  float* sAAi = (float*)alloc((size_t)N * 4);
  int* adj   = (int*)alloc((size_t)2 * E * 4);   // combined: [0,E)=out, [E,2E)=in
  bf16* xb   = (bf16*)alloc((size_t)NX * 2);
  bf16* wt   = (bf16*)alloc((size_t)6 * 4096 * 2);
  float* bsum = (float*)alloc(64 * 4);
  bf16* H  = (bf16*)alloc((size_t)N * KTOT * 2);  // 6 concatenated 64-col slots
  bf16* TQ = (bf16*)alloc((size_t)N * FDIM * 2);
  bf16* TR = (bf16*)alloc((size_t)N * FDIM * 2);

  // dead-before-use aliases (hist/packed consumed before TQ/H are written)
  int* hist   = (int*)TQ;   // 2*NB*NBLK ints  (~4.9 MB  <= 12.8 MB)
  int* packed = (int*)H;    // 2*E ints        (12.8 MB <= 76.8 MB)

  hipMemsetAsync(d_ws, 0, 256, stream);

  int gX = (NX + 255) / 256;
  int gN = (N + 255) / 256;
  int gW = (N + 3) / 4;
  int gF = (N + 63) / 64;

  int NB   = (N + 127) >> 7;        // node buckets (782)
  int NBLK = (E + 2047) >> 11;      // edge blocks  (782)
  int lenH = 2 * NB * NBLK;
  int g0 = (lenH + 255) / 256;
  int g1 = (g0 + 255) / 256;        // <= 1024 required (is ~19)

  // dtype canonicalization
  k_sniff<<<gX, 256, 0, stream>>>((const unsigned short*)x, NX, cnt);
  k_convert_x<<<gX, 256, 0, stream>>>(x, xb, cnt, NX);
  k_convert_w<<<98, 256, 0, stream>>>(d_in[2], d_in[4], d_in[6], d_in[8], d_in[10], d_in[12],
                                      d_in[3], d_in[5], d_in[7], d_in[9], d_in[11], d_in[13],
                                      wt, bsum, cnt);

  // CSR build: histogram -> scan -> bucket scatter -> per-bucket sort (no global atomics)
  k_hist<<<NBLK, 256, 0, stream>>>(row, col, hist, E, NB, NBLK);
  k_scan_block<<<g0, 256, 0, stream>>>(hist, hist, p1, lenH);
  k_scan_block<<<g1, 256, 0, stream>>>(p1, p1, p2, g0);
  k_scan_part<<<1, 1024, 0, stream>>>(p2, g1);
  k_scan_add<<<g1, 256, 0, stream>>>(p1, p2, g0);
  k_scan_add<<<g0, 256, 0, stream>>>(hist, p1, lenH);
  k_bucket_scatter<<<NBLK, 256, 0, stream>>>(row, col, hist, packed, E, NB, NBLK);
  k_bucket_csr<<<2 * NB, 256, 0, stream>>>(hist, packed, adj,
                                           dout_i, roff, din_i, coff,
                                           N, NB, NBLK, 2 * E);
  k_m4scales<<<gN, 256, 0, stream>>>(roff, coff, dout_i, din_i, adj,
                                     iso, isi, sAAt, sAtA, sAAo, sAAi, N);

  // H slots: 0=P1, 1=P2, 2=S0(AAt), 3=Q1->S1(AtA), 4=S2(AA), 5=R1->S3(AtAt)
  k_pass3<<<gW, 256, 0, stream>>>(roff, dout_i, adj, xb, isi, sAAi, sAtA, iso,
                                  H + 0 * 64, H + 5 * 64, TQ, N);
  k_pass3<<<gW, 256, 0, stream>>>(coff, din_i, adj, xb, iso, sAAt, sAAo, isi,
                                  H + 1 * 64, H + 3 * 64, TR, N);
  k_pass2<<<gW, 256, 0, stream>>>(roff, dout_i, adj, H + 3 * 64, H + 5 * 64, KTOT,
                                  sAAt, sAAo, H + 2 * 64, H + 4 * 64, N);
  k_pass2<<<gW, 256, 0, stream>>>(coff, din_i, adj, TQ, TR, FDIM,
                                  sAtA, sAAi, H + 3 * 64, H + 5 * 64, N);

  // out = 0.75 * (H @ Wcat + bsum)
  k_final<<<gF, 256, 0, stream>>>(H, wt, bsum, d_out, cnt, N);
}

// Round 6
// 573.099 us; speedup vs baseline: 4.3891x; 1.2192x over previous
//
#include <hip/hip_runtime.h>
#include <hip/hip_bf16.h>

typedef __hip_bfloat16 bf16;
typedef __bf16 bf16x8 __attribute__((ext_vector_type(8)));
typedef float f32x4 __attribute__((ext_vector_type(4)));
#define FDIM 64
#define KTOT 384
#define LDSK 392   // padded K-stride for W^T in LDS
#define SNIFF_THRESH 100
#define MAXNB 1024 // max node buckets (supports N <= 131072; here N=100K -> 782)

__device__ __forceinline__ float us2f(unsigned short u) {
  union { unsigned int i; float f; } v; v.i = ((unsigned int)u) << 16; return v.f;
}
__device__ __forceinline__ unsigned short f2bu(float v) {
  bf16 h = __float2bfloat16(v);
  return *(unsigned short*)&h;
}
__device__ __forceinline__ float inv_sqrt_pos(float d) { return d > 0.f ? rsqrtf(d) : 0.f; }

// ---------- dtype sniffing & canonicalization ----------
// Sampled sniff: n is capped by host to ~1M elements. fp32-as-u16 -> ~n/256 hits;
// true bf16 of N(0,1)/uniform data -> 0 hits (all-ones exponent = |x|>=3.4e38).
// One atomic per block (256 total) — no single-address contention.
__global__ __launch_bounds__(256)
void k_sniff(const unsigned short* __restrict__ xs, int n, int* __restrict__ cnt) {
  int local = 0;
  for (int i = blockIdx.x * 256 + threadIdx.x; i < n; i += 256 * 256)
    local += ((xs[i] & 0x7F80) == 0x7F80) ? 1 : 0;
  #pragma unroll
  for (int d = 32; d >= 1; d >>= 1) local += __shfl_down(local, d);
  __shared__ int sm[4];
  if ((threadIdx.x & 63) == 0) sm[threadIdx.x >> 6] = local;
  __syncthreads();
  if (threadIdx.x == 0) {
    int t = sm[0] + sm[1] + sm[2] + sm[3];
    if (t) atomicAdd(cnt, t);
  }
}

__global__ void k_convert_x(const void* __restrict__ xin, bf16* __restrict__ xb,
                            const int* __restrict__ cnt, int n) {
  int i = blockIdx.x * 256 + threadIdx.x;
  if (i >= n) return;
  if (*cnt > SNIFF_THRESH) xb[i] = __float2bfloat16(((const float*)xin)[i]);
  else                     xb[i] = ((const bf16*)xin)[i];
}

// W^T-concat: wt[n*384 + si*64 + kk] = W_si[kk][n]; bsum[n] = sum_si b_si[n] (fp32)
__global__ void k_convert_w(const void* W0, const void* W1, const void* W2,
                            const void* W3, const void* W4, const void* W5,
                            const void* c0, const void* c1, const void* c2,
                            const void* c3, const void* c4, const void* c5,
                            bf16* __restrict__ wt, float* __restrict__ bsum,
                            const int* __restrict__ cnt) {
  int t = blockIdx.x * 256 + threadIdx.x;
  const void* Ws[6] = {W0, W1, W2, W3, W4, W5};
  const void* Bs[6] = {c0, c1, c2, c3, c4, c5};
  bool fp = (*cnt > SNIFF_THRESH);
  if (t < 6 * 4096) {
    int si = t >> 12, o = t & 4095;
    int kk = o >> 6, n = o & 63;
    float v = fp ? ((const float*)Ws[si])[o] : __bfloat162float(((const bf16*)Ws[si])[o]);
    wt[n * KTOT + si * 64 + kk] = __float2bfloat16(v);
  } else if (t < 6 * 4096 + 64) {
    int n = t - 6 * 4096;
    float s = 0.f;
    for (int si = 0; si < 6; si++)
      s += fp ? ((const float*)Bs[si])[n] : __bfloat162float(((const bf16*)Bs[si])[n]);
    bsum[n] = s;
  }
}

// ---------- CSR build via LDS counting sort (no global atomics) ----------
__global__ __launch_bounds__(256)
void k_hist(const int* __restrict__ row, const int* __restrict__ col,
            int* __restrict__ hist, int E, int NB, int NBLK) {
  __shared__ int hr[MAXNB], hc[MAXNB];
  for (int i = threadIdx.x; i < NB; i += 256) { hr[i] = 0; hc[i] = 0; }
  __syncthreads();
  int base = blockIdx.x << 11;
  for (int k = 0; k < 8; k++) {
    int e = base + k * 256 + threadIdx.x;
    if (e < E) {
      atomicAdd(&hr[row[e] >> 7], 1);
      atomicAdd(&hc[col[e] >> 7], 1);
    }
  }
  __syncthreads();
  for (int i = threadIdx.x; i < NB; i += 256) {
    hist[(size_t)i * NBLK + blockIdx.x] = hr[i];
    hist[(size_t)(NB + i) * NBLK + blockIdx.x] = hc[i];
  }
}

__global__ void k_scan_block(const int* __restrict__ in, int* __restrict__ out,
                             int* __restrict__ part, int n) {
  __shared__ int sm[256];
  int tid = threadIdx.x;
  int i = blockIdx.x * 256 + tid;
  int v = (i < n) ? in[i] : 0;
  sm[tid] = v;
  __syncthreads();
  for (int d = 1; d < 256; d <<= 1) {
    int t = (tid >= d) ? sm[tid - d] : 0;
    __syncthreads();
    if (tid >= d) sm[tid] += t;
    __syncthreads();
  }
  if (i < n) out[i] = sm[tid] - v;
  if (tid == 255) part[blockIdx.x] = sm[255];
}

__global__ void k_scan_part(int* part, int nb) {
  __shared__ int sm[1024];
  int tid = threadIdx.x;
  int v = (tid < nb) ? part[tid] : 0;
  sm[tid] = v;
  __syncthreads();
  for (int d = 1; d < 1024; d <<= 1) {
    int t = (tid >= d) ? sm[tid - d] : 0;
    __syncthreads();
    if (tid >= d) sm[tid] += t;
    __syncthreads();
  }
  if (tid < nb) part[tid] = sm[tid] - v;
}

__global__ void k_scan_add(int* __restrict__ out, const int* __restrict__ part, int n) {
  int i = blockIdx.x * 256 + threadIdx.x;
  if (i < n) out[i] += part[blockIdx.x];
}

__global__ __launch_bounds__(256)
void k_bucket_scatter(const int* __restrict__ row, const int* __restrict__ col,
                      const int* __restrict__ hist, int* __restrict__ packed,
                      int E, int NB, int NBLK) {
  __shared__ int br[MAXNB], bc[MAXNB];
  for (int i = threadIdx.x; i < NB; i += 256) {
    br[i] = hist[(size_t)i * NBLK + blockIdx.x];
    bc[i] = hist[(size_t)(NB + i) * NBLK + blockIdx.x];
  }
  __syncthreads();
  int base = blockIdx.x << 11;
  for (int k = 0; k < 8; k++) {
    int e = base + k * 256 + threadIdx.x;
    if (e < E) {
      int r = row[e], c = col[e];
      int pr = atomicAdd(&br[r >> 7], 1);
      packed[pr] = (c << 7) | (r & 127);
      int pc = atomicAdd(&bc[c >> 7], 1);
      packed[pc] = (r << 7) | (c & 127);
    }
  }
}

__global__ __launch_bounds__(256)
void k_bucket_csr(const int* __restrict__ hist, const int* __restrict__ packed,
                  int* __restrict__ adj,
                  int* __restrict__ dout, int* __restrict__ roff,
                  int* __restrict__ din, int* __restrict__ coff,
                  int N, int NB, int NBLK, int E2) {
  __shared__ int cnt[128], scn[128], cur[128];
  int gb = blockIdx.x;            // combined bucket index in [0, 2*NB)
  int tid = threadIdx.x;
  if (tid < 128) { cnt[tid] = 0; cur[tid] = 0; }
  __syncthreads();
  int start = hist[(size_t)gb * NBLK];
  int end = (gb + 1 < gridDim.x) ? hist[(size_t)(gb + 1) * NBLK] : E2;
  for (int i = start + tid; i < end; i += 256)
    atomicAdd(&cnt[packed[i] & 127], 1);
  __syncthreads();
  if (tid == 0) {
    int a = 0;
    for (int i = 0; i < 128; i++) { scn[i] = a; a += cnt[i]; }
  }
  __syncthreads();
  if (tid < 128) {
    int b = gb < NB ? gb : gb - NB;
    int node = (b << 7) + tid;
    if (node < N) {
      if (gb < NB) { dout[node] = cnt[tid]; roff[node] = start + scn[tid]; }
      else         { din[node]  = cnt[tid]; coff[node] = start + scn[tid]; }
    }
  }
  __syncthreads();
  for (int i = start + tid; i < end; i += 256) {
    int v = packed[i];
    int l = v & 127, o = v >> 7;
    int rk = atomicAdd(&cur[l], 1);
    adj[start + scn[l] + rk] = o;
  }
}

// Second-order degree sums as CSR gathers + all 6 inv-sqrt scales.
__global__ __launch_bounds__(256)
void k_m4scales(const int* __restrict__ roff, const int* __restrict__ coff,
                const int* __restrict__ dout, const int* __restrict__ din,
                const int* __restrict__ adj,
                float* __restrict__ iso, float* __restrict__ isi,
                float* __restrict__ sAAt, float* __restrict__ sAtA,
                float* __restrict__ sAAo, float* __restrict__ sAAi, int N) {
  int n = blockIdx.x * 256 + threadIdx.x;
  if (n >= N) return;
  int dn = dout[n], cn = din[n];
  int o0 = roff[n];
  float aat = 0.f, aao = 0.f;
  for (int e = 0; e < dn; e++) {
    int c = adj[o0 + e];
    aat += (float)din[c];
    aao += (float)dout[c];
  }
  int i0 = coff[n];
  float ata = 0.f, aai = 0.f;
  for (int e = 0; e < cn; e++) {
    int r = adj[i0 + e];
    ata += (float)dout[r];
    aai += (float)din[r];
  }
  iso[n]  = inv_sqrt_pos((float)dn);
  isi[n]  = inv_sqrt_pos((float)cn);
  sAAt[n] = inv_sqrt_pos(aat);
  sAtA[n] = inv_sqrt_pos(ata);
  sAAo[n] = inv_sqrt_pos(aao);
  sAAi[n] = inv_sqrt_pos(aai);
}

// ---------- SpMM gather passes ----------
__global__ __launch_bounds__(256)
void k_pass3(const int* __restrict__ off, const int* __restrict__ deg,
             const int* __restrict__ adj, const bf16* __restrict__ x,
             const float* __restrict__ s0, const float* __restrict__ s1,
             const float* __restrict__ s2, const float* __restrict__ wsA,
             bf16* __restrict__ outA, bf16* __restrict__ outB, bf16* __restrict__ outC,
             int N) {
  int wid = (blockIdx.x * 256 + threadIdx.x) >> 6;
  if (wid >= N) return;
  int lane = threadIdx.x & 63;
  int q = lane >> 4, t4 = (lane & 15) << 2;
  int o = off[wid], d = deg[wid];
  float a0[4] = {0,0,0,0}, a1[4] = {0,0,0,0}, a2[4] = {0,0,0,0};
  for (int e = q; e < d; e += 4) {
    int nb = adj[o + e];
    ushort4 r = *(const ushort4*)(x + (size_t)nb * FDIM + t4);
    float f0 = us2f(r.x), f1 = us2f(r.y), f2 = us2f(r.z), f3 = us2f(r.w);
    float w0 = s0[nb], w1 = s1[nb], w2 = s2[nb];
    a0[0] += w0 * f0; a0[1] += w0 * f1; a0[2] += w0 * f2; a0[3] += w0 * f3;
    a1[0] += w1 * f0; a1[1] += w1 * f1; a1[2] += w1 * f2; a1[3] += w1 * f3;
    a2[0] += w2 * f0; a2[1] += w2 * f1; a2[2] += w2 * f2; a2[3] += w2 * f3;
  }
  #pragma unroll
  for (int i = 0; i < 4; i++) {
    a0[i] += __shfl_xor(a0[i], 16); a0[i] += __shfl_xor(a0[i], 32);
    a1[i] += __shfl_xor(a1[i], 16); a1[i] += __shfl_xor(a1[i], 32);
    a2[i] += __shfl_xor(a2[i], 16); a2[i] += __shfl_xor(a2[i], 32);
  }
  if (q == 0) {
    float wA = wsA[wid];
    ushort4 uA, uB, uC;
    uA.x = f2bu(a0[0]*wA); uA.y = f2bu(a0[1]*wA); uA.z = f2bu(a0[2]*wA); uA.w = f2bu(a0[3]*wA);
    uB.x = f2bu(a1[0]);    uB.y = f2bu(a1[1]);    uB.z = f2bu(a1[2]);    uB.w = f2bu(a1[3]);
    uC.x = f2bu(a2[0]);    uC.y = f2bu(a2[1]);    uC.z = f2bu(a2[2]);    uC.w = f2bu(a2[3]);
    *(ushort4*)(outA + (size_t)wid * KTOT + t4) = uA;
    *(ushort4*)(outB + (size_t)wid * KTOT + t4) = uB;
    *(ushort4*)(outC + (size_t)wid * FDIM + t4) = uC;
  }
}

__global__ __launch_bounds__(256)
void k_pass2(const int* __restrict__ off, const int* __restrict__ deg,
             const int* __restrict__ adj,
             const bf16* __restrict__ inA, const bf16* __restrict__ inB, int strideIn,
             const float* __restrict__ wsA, const float* __restrict__ wsB,
             bf16* __restrict__ outA, bf16* __restrict__ outB, int N) {
  int wid = (blockIdx.x * 256 + threadIdx.x) >> 6;
  if (wid >= N) return;
  int lane = threadIdx.x & 63;
  int q = lane >> 4, t4 = (lane & 15) << 2;
  int o = off[wid], d = deg[wid];
  float a0[4] = {0,0,0,0}, a1[4] = {0,0,0,0};
  for (int e = q; e < d; e += 4) {
    int nb = adj[o + e];
    ushort4 rA = *(const ushort4*)(inA + (size_t)nb * strideIn + t4);
    ushort4 rB = *(const ushort4*)(inB + (size_t)nb * strideIn + t4);
    a0[0] += us2f(rA.x); a0[1] += us2f(rA.y); a0[2] += us2f(rA.z); a0[3] += us2f(rA.w);
    a1[0] += us2f(rB.x); a1[1] += us2f(rB.y); a1[2] += us2f(rB.z); a1[3] += us2f(rB.w);
  }
  #pragma unroll
  for (int i = 0; i < 4; i++) {
    a0[i] += __shfl_xor(a0[i], 16); a0[i] += __shfl_xor(a0[i], 32);
    a1[i] += __shfl_xor(a1[i], 16); a1[i] += __shfl_xor(a1[i], 32);
  }
  if (q == 0) {
    float wA = wsA[wid], wB = wsB[wid];
    ushort4 uA, uB;
    uA.x = f2bu(a0[0]*wA); uA.y = f2bu(a0[1]*wA); uA.z = f2bu(a0[2]*wA); uA.w = f2bu(a0[3]*wA);
    uB.x = f2bu(a1[0]*wB); uB.y = f2bu(a1[1]*wB); uB.z = f2bu(a1[2]*wB); uB.w = f2bu(a1[3]*wB);
    *(ushort4*)(outA + (size_t)wid * KTOT + t4) = uA;
    *(ushort4*)(outB + (size_t)wid * KTOT + t4) = uB;
  }
}

// ---------- final MFMA GEMM: out[N,64] = 0.75*(H[N,384] @ Wcat[384,64] + bsum) ----------
__global__ __launch_bounds__(256)
void k_final(const bf16* __restrict__ H, const bf16* __restrict__ wt,
             const float* __restrict__ bsum, void* __restrict__ outv,
             const int* __restrict__ cnt, int N) {
  __shared__ bf16 Wl[64 * LDSK];
  {
    const unsigned int* wtu = (const unsigned int*)wt;
    unsigned int* wlu = (unsigned int*)Wl;
    for (int i = threadIdx.x; i < 64 * (KTOT / 2); i += 256) {
      int n = i / (KTOT / 2), k2 = i % (KTOT / 2);
      wlu[n * (LDSK / 2) + k2] = wtu[i];
    }
  }
  __syncthreads();

  int wave = threadIdx.x >> 6, lane = threadIdx.x & 63;
  int m0 = blockIdx.x * 64 + wave * 16;
  int ml = lane & 15, kq = lane >> 4;
  const bf16* Hrow = H + (size_t)(m0 + ml) * KTOT + kq * 8;

  f32x4 acc[4] = {{0,0,0,0},{0,0,0,0},{0,0,0,0},{0,0,0,0}};
  #pragma unroll
  for (int kb = 0; kb < KTOT / 32; kb++) {
    bf16x8 a = *(const bf16x8*)(Hrow + kb * 32);
    #pragma unroll
    for (int ct = 0; ct < 4; ct++) {
      bf16x8 b = *(const bf16x8*)(Wl + (size_t)(ct * 16 + ml) * LDSK + kb * 32 + kq * 8);
      acc[ct] = __builtin_amdgcn_mfma_f32_16x16x32_bf16(a, b, acc[ct], 0, 0, 0);
    }
  }

  bool fp = (*cnt > SNIFF_THRESH);
  #pragma unroll
  for (int ct = 0; ct < 4; ct++) {
    int col = ct * 16 + ml;
    float bias = bsum[col];
    #pragma unroll
    for (int r = 0; r < 4; r++) {
      int m = m0 + kq * 4 + r;
      if (m < N) {
        float val = 0.75f * (acc[ct][r] + bias);
        if (fp) ((float*)outv)[(size_t)m * FDIM + col] = val;
        else    ((bf16*)outv)[(size_t)m * FDIM + col] = __float2bfloat16(val);
      }
    }
  }
}

// ---------- host ----------
extern "C" void kernel_launch(void* const* d_in, const int* in_sizes, int n_in,
                              void* d_out, int out_size, void* d_ws, size_t ws_size,
                              hipStream_t stream) {
  const void* x = d_in[0];
  const int* ei = (const int*)d_in[1];
  int NX = in_sizes[0];
  int N = NX / FDIM;
  int E = in_sizes[1] / 2;
  const int* row = ei;
  const int* col = ei + E;

  char* p = (char*)d_ws;
  auto alloc = [&](size_t bytes) {
    bytes = (bytes + 255) & ~(size_t)255;
    char* r = p; p += bytes; return r;
  };

  int*   cnt    = (int*)alloc(4);          // zero-init
  int*   dout_i = (int*)alloc((size_t)N * 4);
  int*   din_i  = (int*)alloc((size_t)N * 4);
  int* roff  = (int*)alloc((size_t)N * 4);
  int* coff  = (int*)alloc((size_t)N * 4);
  int* p1    = (int*)alloc(8192 * 4);
  int* p2    = (int*)alloc(1024 * 4);
  float* iso  = (float*)alloc((size_t)N * 4);
  float* isi  = (float*)alloc((size_t)N * 4);
  float* sAAt = (float*)alloc((size_t)N * 4);
  float* sAtA = (float*)alloc((size_t)N * 4);
  float* sAAo = (float*)alloc((size_t)N * 4);
  float* sAAi = (float*)alloc((size_t)N * 4);
  int* adj   = (int*)alloc((size_t)2 * E * 4);   // combined: [0,E)=out, [E,2E)=in
  bf16* xb   = (bf16*)alloc((size_t)NX * 2);
  bf16* wt   = (bf16*)alloc((size_t)6 * 4096 * 2);
  float* bsum = (float*)alloc(64 * 4);
  bf16* H  = (bf16*)alloc((size_t)N * KTOT * 2);  // 6 concatenated 64-col slots
  bf16* TQ = (bf16*)alloc((size_t)N * FDIM * 2);
  bf16* TR = (bf16*)alloc((size_t)N * FDIM * 2);

  // dead-before-use aliases (hist/packed consumed before TQ/H are written)
  int* hist   = (int*)TQ;   // 2*NB*NBLK ints  (~4.9 MB  <= 12.8 MB)
  int* packed = (int*)H;    // 2*E ints        (12.8 MB <= 76.8 MB)

  hipMemsetAsync(d_ws, 0, 256, stream);

  int gX = (NX + 255) / 256;
  int gN = (N + 255) / 256;
  int gW = (N + 3) / 4;
  int gF = (N + 63) / 64;

  int NB   = (N + 127) >> 7;        // node buckets (782)
  int NBLK = (E + 2047) >> 11;      // edge blocks  (782)
  int lenH = 2 * NB * NBLK;
  int g0 = (lenH + 255) / 256;
  int g1 = (g0 + 255) / 256;

  // dtype canonicalization (sampled sniff: 1M elements, 1 atomic/block)
  int nSniff = NX < (1 << 20) ? NX : (1 << 20);
  k_sniff<<<256, 256, 0, stream>>>((const unsigned short*)x, nSniff, cnt);
  k_convert_x<<<gX, 256, 0, stream>>>(x, xb, cnt, NX);
  k_convert_w<<<98, 256, 0, stream>>>(d_in[2], d_in[4], d_in[6], d_in[8], d_in[10], d_in[12],
                                      d_in[3], d_in[5], d_in[7], d_in[9], d_in[11], d_in[13],
                                      wt, bsum, cnt);

  // CSR build: histogram -> scan -> bucket scatter -> per-bucket sort (no global atomics)
  k_hist<<<NBLK, 256, 0, stream>>>(row, col, hist, E, NB, NBLK);
  k_scan_block<<<g0, 256, 0, stream>>>(hist, hist, p1, lenH);
  k_scan_block<<<g1, 256, 0, stream>>>(p1, p1, p2, g0);
  k_scan_part<<<1, 1024, 0, stream>>>(p2, g1);
  k_scan_add<<<g1, 256, 0, stream>>>(p1, p2, g0);
  k_scan_add<<<g0, 256, 0, stream>>>(hist, p1, lenH);
  k_bucket_scatter<<<NBLK, 256, 0, stream>>>(row, col, hist, packed, E, NB, NBLK);
  k_bucket_csr<<<2 * NB, 256, 0, stream>>>(hist, packed, adj,
                                           dout_i, roff, din_i, coff,
                                           N, NB, NBLK, 2 * E);
  k_m4scales<<<gN, 256, 0, stream>>>(roff, coff, dout_i, din_i, adj,
                                     iso, isi, sAAt, sAtA, sAAo, sAAi, N);

  // H slots: 0=P1, 1=P2, 2=S0(AAt), 3=Q1->S1(AtA), 4=S2(AA), 5=R1->S3(AtAt)
  k_pass3<<<gW, 256, 0, stream>>>(roff, dout_i, adj, xb, isi, sAAi, sAtA, iso,
                                  H + 0 * 64, H + 5 * 64, TQ, N);
  k_pass3<<<gW, 256, 0, stream>>>(coff, din_i, adj, xb, iso, sAAt, sAAo, isi,
                                  H + 1 * 64, H + 3 * 64, TR, N);
  k_pass2<<<gW, 256, 0, stream>>>(roff, dout_i, adj, H + 3 * 64, H + 5 * 64, KTOT,
                                  sAAt, sAAo, H + 2 * 64, H + 4 * 64, N);
  k_pass2<<<gW, 256, 0, stream>>>(coff, din_i, adj, TQ, TR, FDIM,
                                  sAtA, sAAi, H + 3 * 64, H + 5 * 64, N);

  // out = 0.75 * (H @ Wcat + bsum)
  k_final<<<gF, 256, 0, stream>>>(H, wt, bsum, d_out, cnt, N);
}

// Round 7
// 548.667 us; speedup vs baseline: 4.5845x; 1.0445x over previous
//
#include <hip/hip_runtime.h>
#include <hip/hip_bf16.h>

typedef __hip_bfloat16 bf16;
typedef __bf16 bf16x8 __attribute__((ext_vector_type(8)));
typedef float f32x4 __attribute__((ext_vector_type(4)));
#define FDIM 64
#define KTOT 384
#define LDSK 392   // padded K-stride for W^T in LDS
#define SNIFF_THRESH 100
#define MAXNB 1024 // max node buckets (supports N <= 131072; here N=100K -> 782)

__device__ __forceinline__ float us2f(unsigned short u) {
  union { unsigned int i; float f; } v; v.i = ((unsigned int)u) << 16; return v.f;
}
__device__ __forceinline__ unsigned short f2bu(float v) {
  bf16 h = __float2bfloat16(v);
  return *(unsigned short*)&h;
}
__device__ __forceinline__ unsigned int pack2(float a, float b) {
  return (unsigned int)f2bu(a) | ((unsigned int)f2bu(b) << 16);
}
__device__ __forceinline__ float inv_sqrt_pos(float d) { return d > 0.f ? rsqrtf(d) : 0.f; }

// ---------- dtype sniffing & canonicalization ----------
__global__ __launch_bounds__(256)
void k_sniff(const unsigned short* __restrict__ xs, int n, int* __restrict__ cnt) {
  int local = 0;
  for (int i = blockIdx.x * 256 + threadIdx.x; i < n; i += 256 * 256)
    local += ((xs[i] & 0x7F80) == 0x7F80) ? 1 : 0;
  #pragma unroll
  for (int d = 32; d >= 1; d >>= 1) local += __shfl_down(local, d);
  __shared__ int sm[4];
  if ((threadIdx.x & 63) == 0) sm[threadIdx.x >> 6] = local;
  __syncthreads();
  if (threadIdx.x == 0) {
    int t = sm[0] + sm[1] + sm[2] + sm[3];
    if (t) atomicAdd(cnt, t);
  }
}

__global__ void k_convert_x(const void* __restrict__ xin, bf16* __restrict__ xb,
                            const int* __restrict__ cnt, int n) {
  int i = blockIdx.x * 256 + threadIdx.x;
  if (i >= n) return;
  if (*cnt > SNIFF_THRESH) xb[i] = __float2bfloat16(((const float*)xin)[i]);
  else                     xb[i] = ((const bf16*)xin)[i];
}

// W^T-concat: wt[n*384 + si*64 + kk] = W_si[kk][n]; bsum[n] = sum_si b_si[n] (fp32)
__global__ void k_convert_w(const void* W0, const void* W1, const void* W2,
                            const void* W3, const void* W4, const void* W5,
                            const void* c0, const void* c1, const void* c2,
                            const void* c3, const void* c4, const void* c5,
                            bf16* __restrict__ wt, float* __restrict__ bsum,
                            const int* __restrict__ cnt) {
  int t = blockIdx.x * 256 + threadIdx.x;
  const void* Ws[6] = {W0, W1, W2, W3, W4, W5};
  const void* Bs[6] = {c0, c1, c2, c3, c4, c5};
  bool fp = (*cnt > SNIFF_THRESH);
  if (t < 6 * 4096) {
    int si = t >> 12, o = t & 4095;
    int kk = o >> 6, n = o & 63;
    float v = fp ? ((const float*)Ws[si])[o] : __bfloat162float(((const bf16*)Ws[si])[o]);
    wt[n * KTOT + si * 64 + kk] = __float2bfloat16(v);
  } else if (t < 6 * 4096 + 64) {
    int n = t - 6 * 4096;
    float s = 0.f;
    for (int si = 0; si < 6; si++)
      s += fp ? ((const float*)Bs[si])[n] : __bfloat162float(((const bf16*)Bs[si])[n]);
    bsum[n] = s;
  }
}

// ---------- CSR build via LDS counting sort (no global atomics) ----------
__global__ __launch_bounds__(256)
void k_hist(const int* __restrict__ row, const int* __restrict__ col,
            int* __restrict__ hist, int E, int NB, int NBLK) {
  __shared__ int hr[MAXNB], hc[MAXNB];
  for (int i = threadIdx.x; i < NB; i += 256) { hr[i] = 0; hc[i] = 0; }
  __syncthreads();
  int base = blockIdx.x << 11;
  for (int k = 0; k < 8; k++) {
    int e = base + k * 256 + threadIdx.x;
    if (e < E) {
      atomicAdd(&hr[row[e] >> 7], 1);
      atomicAdd(&hc[col[e] >> 7], 1);
    }
  }
  __syncthreads();
  for (int i = threadIdx.x; i < NB; i += 256) {
    hist[(size_t)i * NBLK + blockIdx.x] = hr[i];
    hist[(size_t)(NB + i) * NBLK + blockIdx.x] = hc[i];
  }
}

__global__ void k_scan_block(const int* __restrict__ in, int* __restrict__ out,
                             int* __restrict__ part, int n) {
  __shared__ int sm[256];
  int tid = threadIdx.x;
  int i = blockIdx.x * 256 + tid;
  int v = (i < n) ? in[i] : 0;
  sm[tid] = v;
  __syncthreads();
  for (int d = 1; d < 256; d <<= 1) {
    int t = (tid >= d) ? sm[tid - d] : 0;
    __syncthreads();
    if (tid >= d) sm[tid] += t;
    __syncthreads();
  }
  if (i < n) out[i] = sm[tid] - v;
  if (tid == 255) part[blockIdx.x] = sm[255];
}

__global__ void k_scan_part(int* part, int nb) {
  __shared__ int sm[1024];
  int tid = threadIdx.x;
  int v = (tid < nb) ? part[tid] : 0;
  sm[tid] = v;
  __syncthreads();
  for (int d = 1; d < 1024; d <<= 1) {
    int t = (tid >= d) ? sm[tid - d] : 0;
    __syncthreads();
    if (tid >= d) sm[tid] += t;
    __syncthreads();
  }
  if (tid < nb) part[tid] = sm[tid] - v;
}

__global__ void k_scan_add(int* __restrict__ out, const int* __restrict__ part, int n) {
  int i = blockIdx.x * 256 + threadIdx.x;
  if (i < n) out[i] += part[blockIdx.x];
}

__global__ __launch_bounds__(256)
void k_bucket_scatter(const int* __restrict__ row, const int* __restrict__ col,
                      const int* __restrict__ hist, int* __restrict__ packed,
                      int E, int NB, int NBLK) {
  __shared__ int br[MAXNB], bc[MAXNB];
  for (int i = threadIdx.x; i < NB; i += 256) {
    br[i] = hist[(size_t)i * NBLK + blockIdx.x];
    bc[i] = hist[(size_t)(NB + i) * NBLK + blockIdx.x];
  }
  __syncthreads();
  int base = blockIdx.x << 11;
  for (int k = 0; k < 8; k++) {
    int e = base + k * 256 + threadIdx.x;
    if (e < E) {
      int r = row[e], c = col[e];
      int pr = atomicAdd(&br[r >> 7], 1);
      packed[pr] = (c << 7) | (r & 127);
      int pc = atomicAdd(&bc[c >> 7], 1);
      packed[pc] = (r << 7) | (c & 127);
    }
  }
}

// One block per (direction, bucket): per-node counts -> deg2 fields, offsets, sorted adj.
__global__ __launch_bounds__(256)
void k_bucket_csr(const int* __restrict__ hist, const int* __restrict__ packed,
                  int* __restrict__ adj, int2* __restrict__ deg2,
                  int* __restrict__ roff, int* __restrict__ coff,
                  int N, int NB, int NBLK, int E2) {
  __shared__ int cnt[128], scn[128], cur[128];
  int gb = blockIdx.x;            // combined bucket index in [0, 2*NB)
  int tid = threadIdx.x;
  if (tid < 128) { cnt[tid] = 0; cur[tid] = 0; }
  __syncthreads();
  int start = hist[(size_t)gb * NBLK];
  int end = (gb + 1 < gridDim.x) ? hist[(size_t)(gb + 1) * NBLK] : E2;
  for (int i = start + tid; i < end; i += 256)
    atomicAdd(&cnt[packed[i] & 127], 1);
  __syncthreads();
  if (tid == 0) {
    int a = 0;
    for (int i = 0; i < 128; i++) { scn[i] = a; a += cnt[i]; }
  }
  __syncthreads();
  if (tid < 128) {
    int b = gb < NB ? gb : gb - NB;
    int node = (b << 7) + tid;
    if (node < N) {
      if (gb < NB) { deg2[node].x = cnt[tid]; roff[node] = start + scn[tid]; }
      else         { deg2[node].y = cnt[tid]; coff[node] = start + scn[tid]; }
    }
  }
  __syncthreads();
  for (int i = start + tid; i < end; i += 256) {
    int v = packed[i];
    int l = v & 127, o = v >> 7;
    int rk = atomicAdd(&cur[l], 1);
    adj[start + scn[l] + rk] = o;
  }
}

// Second-order degree sums (CSR gathers of packed int2 degrees) + packed scale vectors.
// sclG1[n] = {isi, sAtA, sAAi, iso}  (gathered by pass A; .w = A's write scale)
// sclG2[n] = {iso, sAAt, sAAo, isi}  (gathered by pass B; .w = B's write scale)
__global__ __launch_bounds__(256)
void k_m4scales(const int* __restrict__ roff, const int* __restrict__ coff,
                const int2* __restrict__ deg2, const int* __restrict__ adj,
                float4* __restrict__ sclG1, float4* __restrict__ sclG2, int N) {
  int n = blockIdx.x * 256 + threadIdx.x;
  if (n >= N) return;
  int2 dn = deg2[n];
  int o0 = roff[n];
  float aat = 0.f, aao = 0.f;
  for (int e = 0; e < dn.x; e++) {
    int2 dc = deg2[adj[o0 + e]];
    aat += (float)dc.y;   // Av(d_in)
    aao += (float)dc.x;   // Av(d_out)
  }
  int i0 = coff[n];
  float ata = 0.f, aai = 0.f;
  for (int e = 0; e < dn.y; e++) {
    int2 dr = deg2[adj[i0 + e]];
    ata += (float)dr.x;   // Atv(d_out)
    aai += (float)dr.y;   // Atv(d_in)
  }
  float iso = inv_sqrt_pos((float)dn.x), isi = inv_sqrt_pos((float)dn.y);
  sclG1[n] = make_float4(isi, inv_sqrt_pos(ata), inv_sqrt_pos(aai), iso);
  sclG2[n] = make_float4(iso, inv_sqrt_pos(aat), inv_sqrt_pos(aao), isi);
}

// ---------- fused first-order passes: A (out-CSR/Av) + B (in-CSR/Atv) ----------
// A: P1 -> H slot0 (*iso); Q2 -> QR2 cols0-63; R1 -> QR1 cols64-127
// B: P2 -> H slot1 (*isi); Q1 -> QR1 cols0-63; R2 -> QR2 cols64-127
__global__ __launch_bounds__(256)
void k_passAB(const int* __restrict__ roff, const int* __restrict__ coff,
              const int2* __restrict__ deg2, const int* __restrict__ adj,
              const bf16* __restrict__ xb,
              const float4* __restrict__ sclG1, const float4* __restrict__ sclG2,
              bf16* __restrict__ H, bf16* __restrict__ QR1, bf16* __restrict__ QR2,
              int N, int gW) {
  int side = (blockIdx.x >= gW);
  int lb = side ? blockIdx.x - gW : blockIdx.x;
  int wid = (lb * 256 + (int)threadIdx.x) >> 6;
  if (wid >= N) return;
  int lane = threadIdx.x & 63;
  int q = lane >> 4, t4 = (lane & 15) << 2;
  int o, d; const float4* sclG; bf16 *outP, *outOwn, *outOth;
  if (!side) { o = roff[wid]; d = deg2[wid].x; sclG = sclG1;
               outP = H + 0 * 64; outOwn = QR2; outOth = QR1; }
  else       { o = coff[wid]; d = deg2[wid].y; sclG = sclG2;
               outP = H + 1 * 64; outOwn = QR1; outOth = QR2; }
  float a0[4] = {0,0,0,0}, a1[4] = {0,0,0,0}, a2[4] = {0,0,0,0};
  for (int e = q; e < d; e += 4) {
    int nb = adj[o + e];
    ushort4 r = *(const ushort4*)(xb + (size_t)nb * FDIM + t4);
    float4 s = sclG[nb];
    float f0 = us2f(r.x), f1 = us2f(r.y), f2 = us2f(r.z), f3 = us2f(r.w);
    a0[0] += s.x * f0; a0[1] += s.x * f1; a0[2] += s.x * f2; a0[3] += s.x * f3;
    a1[0] += s.y * f0; a1[1] += s.y * f1; a1[2] += s.y * f2; a1[3] += s.y * f3;
    a2[0] += s.z * f0; a2[1] += s.z * f1; a2[2] += s.z * f2; a2[3] += s.z * f3;
  }
  #pragma unroll
  for (int i = 0; i < 4; i++) {
    a0[i] += __shfl_xor(a0[i], 16); a0[i] += __shfl_xor(a0[i], 32);
    a1[i] += __shfl_xor(a1[i], 16); a1[i] += __shfl_xor(a1[i], 32);
    a2[i] += __shfl_xor(a2[i], 16); a2[i] += __shfl_xor(a2[i], 32);
  }
  if (q == 0) {
    float w = sclG[wid].w;
    ushort4 uP, uQ, uR;
    uP.x = f2bu(a0[0]*w); uP.y = f2bu(a0[1]*w); uP.z = f2bu(a0[2]*w); uP.w = f2bu(a0[3]*w);
    uQ.x = f2bu(a1[0]);   uQ.y = f2bu(a1[1]);   uQ.z = f2bu(a1[2]);   uQ.w = f2bu(a1[3]);
    uR.x = f2bu(a2[0]);   uR.y = f2bu(a2[1]);   uR.z = f2bu(a2[2]);   uR.w = f2bu(a2[3]);
    *(ushort4*)(outP + (size_t)wid * KTOT + t4) = uP;
    *(ushort4*)(outOwn + (size_t)wid * 128 + t4) = uQ;
    *(ushort4*)(outOth + (size_t)wid * 128 + 64 + t4) = uR;
  }
}

// ---------- fused second-order passes: C (out-CSR, QR1) + D (in-CSR, QR2) ----------
// One contiguous 256B gather per edge (16 lanes x uint4).
// C: S0=sAAt*Av(Q1)->slot2, S2=sAAo*Av(R1)->slot4;  D: S1=sAtA*Atv(Q2)->slot3, S3=sAAi*Atv(R2)->slot5
__global__ __launch_bounds__(256)
void k_passCD(const int* __restrict__ roff, const int* __restrict__ coff,
              const int2* __restrict__ deg2, const int* __restrict__ adj,
              const bf16* __restrict__ QR1, const bf16* __restrict__ QR2,
              const float4* __restrict__ sclG1, const float4* __restrict__ sclG2,
              bf16* __restrict__ H, int N, int gW) {
  int side = (blockIdx.x >= gW);   // 0 = C, 1 = D
  int lb = side ? blockIdx.x - gW : blockIdx.x;
  int wid = (lb * 256 + (int)threadIdx.x) >> 6;
  if (wid >= N) return;
  int lane = threadIdx.x & 63;
  int q = lane >> 4, t = lane & 15;
  int o, d; const bf16* QR;
  if (!side) { o = roff[wid]; d = deg2[wid].x; QR = QR1; }
  else       { o = coff[wid]; d = deg2[wid].y; QR = QR2; }
  float acc[8] = {0,0,0,0,0,0,0,0};
  for (int e = q; e < d; e += 4) {
    int nb = adj[o + e];
    uint4 v = *(const uint4*)(QR + (size_t)nb * 128 + t * 8);
    acc[0] += us2f(v.x & 0xffff); acc[1] += us2f(v.x >> 16);
    acc[2] += us2f(v.y & 0xffff); acc[3] += us2f(v.y >> 16);
    acc[4] += us2f(v.z & 0xffff); acc[5] += us2f(v.z >> 16);
    acc[6] += us2f(v.w & 0xffff); acc[7] += us2f(v.w >> 16);
  }
  #pragma unroll
  for (int i = 0; i < 8; i++) {
    acc[i] += __shfl_xor(acc[i], 16);
    acc[i] += __shfl_xor(acc[i], 32);
  }
  if (q == 0) {
    float4 s = side ? sclG1[wid] : sclG2[wid];
    float ws = (t < 8) ? s.y : s.z;
    int slot = side ? (t < 8 ? 3 : 5) : (t < 8 ? 2 : 4);
    int col = slot * 64 + (t & 7) * 8;
    uint4 ov;
    ov.x = pack2(acc[0]*ws, acc[1]*ws);
    ov.y = pack2(acc[2]*ws, acc[3]*ws);
    ov.z = pack2(acc[4]*ws, acc[5]*ws);
    ov.w = pack2(acc[6]*ws, acc[7]*ws);
    *(uint4*)(H + (size_t)wid * KTOT + col) = ov;
  }
}

// ---------- final MFMA GEMM: out[N,64] = 0.75*(H[N,384] @ Wcat[384,64] + bsum) ----------
__global__ __launch_bounds__(256)
void k_final(const bf16* __restrict__ H, const bf16* __restrict__ wt,
             const float* __restrict__ bsum, void* __restrict__ outv,
             const int* __restrict__ cnt, int N) {
  __shared__ bf16 Wl[64 * LDSK];
  {
    const unsigned int* wtu = (const unsigned int*)wt;
    unsigned int* wlu = (unsigned int*)Wl;
    for (int i = threadIdx.x; i < 64 * (KTOT / 2); i += 256) {
      int n = i / (KTOT / 2), k2 = i % (KTOT / 2);
      wlu[n * (LDSK / 2) + k2] = wtu[i];
    }
  }
  __syncthreads();

  int wave = threadIdx.x >> 6, lane = threadIdx.x & 63;
  int m0 = blockIdx.x * 64 + wave * 16;
  int ml = lane & 15, kq = lane >> 4;
  const bf16* Hrow = H + (size_t)(m0 + ml) * KTOT + kq * 8;

  f32x4 acc[4] = {{0,0,0,0},{0,0,0,0},{0,0,0,0},{0,0,0,0}};
  #pragma unroll
  for (int kb = 0; kb < KTOT / 32; kb++) {
    bf16x8 a = *(const bf16x8*)(Hrow + kb * 32);
    #pragma unroll
    for (int ct = 0; ct < 4; ct++) {
      bf16x8 b = *(const bf16x8*)(Wl + (size_t)(ct * 16 + ml) * LDSK + kb * 32 + kq * 8);
      acc[ct] = __builtin_amdgcn_mfma_f32_16x16x32_bf16(a, b, acc[ct], 0, 0, 0);
    }
  }

  bool fp = (*cnt > SNIFF_THRESH);
  #pragma unroll
  for (int ct = 0; ct < 4; ct++) {
    int col = ct * 16 + ml;
    float bias = bsum[col];
    #pragma unroll
    for (int r = 0; r < 4; r++) {
      int m = m0 + kq * 4 + r;
      if (m < N) {
        float val = 0.75f * (acc[ct][r] + bias);
        if (fp) ((float*)outv)[(size_t)m * FDIM + col] = val;
        else    ((bf16*)outv)[(size_t)m * FDIM + col] = __float2bfloat16(val);
      }
    }
  }
}

// ---------- host ----------
extern "C" void kernel_launch(void* const* d_in, const int* in_sizes, int n_in,
                              void* d_out, int out_size, void* d_ws, size_t ws_size,
                              hipStream_t stream) {
  const void* x = d_in[0];
  const int* ei = (const int*)d_in[1];
  int NX = in_sizes[0];
  int N = NX / FDIM;
  int E = in_sizes[1] / 2;
  const int* row = ei;
  const int* col = ei + E;

  char* p = (char*)d_ws;
  auto alloc = [&](size_t bytes) {
    bytes = (bytes + 255) & ~(size_t)255;
    char* r = p; p += bytes; return r;
  };

  int*   cnt  = (int*)alloc(4);            // zero-init region start
  int2*  deg2 = (int2*)alloc((size_t)N * 8);
  int* roff   = (int*)alloc((size_t)N * 4);
  int* coff   = (int*)alloc((size_t)N * 4);
  int* p1     = (int*)alloc(8192 * 4);
  int* p2     = (int*)alloc(1024 * 4);
  float4* sclG1 = (float4*)alloc((size_t)N * 16);
  float4* sclG2 = (float4*)alloc((size_t)N * 16);
  int* adj    = (int*)alloc((size_t)2 * E * 4);  // [0,E)=out-CSR, [E,2E)=in-CSR
  bf16* xb    = (bf16*)alloc((size_t)NX * 2);
  bf16* wt    = (bf16*)alloc((size_t)6 * 4096 * 2);
  float* bsum = (float*)alloc(64 * 4);
  bf16* H   = (bf16*)alloc((size_t)N * KTOT * 2); // 6 concatenated 64-col slots
  bf16* QR1 = (bf16*)alloc((size_t)N * 128 * 2);  // [Q1 | R1]
  bf16* QR2 = (bf16*)alloc((size_t)N * 128 * 2);  // [Q2 | R2]

  // dead-before-use aliases (consumed in CSR build, before QR1/H are written)
  int* hist   = (int*)QR1;  // 2*NB*NBLK ints (~4.9 MB <= 25.6 MB)
  int* packed = (int*)H;    // 2*E ints (12.8 MB <= 76.8 MB)

  hipMemsetAsync(d_ws, 0, 256, stream);

  int gX = (NX + 255) / 256;
  int gN = (N + 255) / 256;
  int gW = (N + 3) / 4;      // wave-per-node kernels: 4 waves/block
  int gF = (N + 63) / 64;

  int NB   = (N + 127) >> 7;
  int NBLK = (E + 2047) >> 11;
  int lenH = 2 * NB * NBLK;
  int g0 = (lenH + 255) / 256;
  int g1 = (g0 + 255) / 256;

  // dtype canonicalization (sampled sniff: 1M elements, 1 atomic/block)
  int nSniff = NX < (1 << 20) ? NX : (1 << 20);
  k_sniff<<<256, 256, 0, stream>>>((const unsigned short*)x, nSniff, cnt);
  k_convert_x<<<gX, 256, 0, stream>>>(x, xb, cnt, NX);
  k_convert_w<<<98, 256, 0, stream>>>(d_in[2], d_in[4], d_in[6], d_in[8], d_in[10], d_in[12],
                                      d_in[3], d_in[5], d_in[7], d_in[9], d_in[11], d_in[13],
                                      wt, bsum, cnt);

  // CSR build: histogram -> scan -> bucket scatter -> per-bucket sort (no global atomics)
  k_hist<<<NBLK, 256, 0, stream>>>(row, col, hist, E, NB, NBLK);
  k_scan_block<<<g0, 256, 0, stream>>>(hist, hist, p1, lenH);
  k_scan_block<<<g1, 256, 0, stream>>>(p1, p1, p2, g0);
  k_scan_part<<<1, 1024, 0, stream>>>(p2, g1);
  k_scan_add<<<g1, 256, 0, stream>>>(p1, p2, g0);
  k_scan_add<<<g0, 256, 0, stream>>>(hist, p1, lenH);
  k_bucket_scatter<<<NBLK, 256, 0, stream>>>(row, col, hist, packed, E, NB, NBLK);
  k_bucket_csr<<<2 * NB, 256, 0, stream>>>(hist, packed, adj, deg2, roff, coff,
                                           N, NB, NBLK, 2 * E);
  k_m4scales<<<gN, 256, 0, stream>>>(roff, coff, deg2, adj, sclG1, sclG2, N);

  // fused first-order (A+B) and second-order (C+D) passes
  k_passAB<<<2 * gW, 256, 0, stream>>>(roff, coff, deg2, adj, xb, sclG1, sclG2,
                                       H, QR1, QR2, N, gW);
  k_passCD<<<2 * gW, 256, 0, stream>>>(roff, coff, deg2, adj, QR1, QR2, sclG1, sclG2,
                                       H, N, gW);

  // out = 0.75 * (H @ Wcat + bsum)
  k_final<<<gF, 256, 0, stream>>>(H, wt, bsum, d_out, cnt, N);
}

// Round 9
// 547.333 us; speedup vs baseline: 4.5957x; 1.0024x over previous
//
#include <hip/hip_runtime.h>
#include <hip/hip_bf16.h>

typedef __hip_bfloat16 bf16;
typedef __bf16 bf16x8 __attribute__((ext_vector_type(8)));
typedef float f32x4 __attribute__((ext_vector_type(4)));
#define FDIM 64
#define KTOT 384
#define LDSK 392   // padded K-stride for W^T in LDS
#define SNIFF_THRESH 100
#define MAXNB 1024 // max node buckets (supports N <= 131072; here N=100K -> 782)

__device__ __forceinline__ float us2f(unsigned short u) {
  union { unsigned int i; float f; } v; v.i = ((unsigned int)u) << 16; return v.f;
}
__device__ __forceinline__ unsigned short f2bu(float v) {
  bf16 h = __float2bfloat16(v);
  return *(unsigned short*)&h;
}
__device__ __forceinline__ unsigned int pack2(float a, float b) {
  return (unsigned int)f2bu(a) | ((unsigned int)f2bu(b) << 16);
}
__device__ __forceinline__ float inv_sqrt_pos(float d) { return d > 0.f ? rsqrtf(d) : 0.f; }

// ---------- dtype sniffing & canonicalization ----------
__global__ __launch_bounds__(256)
void k_sniff(const unsigned short* __restrict__ xs, int n, int* __restrict__ cnt) {
  int local = 0;
  for (int i = blockIdx.x * 256 + threadIdx.x; i < n; i += 256 * 256)
    local += ((xs[i] & 0x7F80) == 0x7F80) ? 1 : 0;
  #pragma unroll
  for (int d = 32; d >= 1; d >>= 1) local += __shfl_down(local, d);
  __shared__ int sm[4];
  if ((threadIdx.x & 63) == 0) sm[threadIdx.x >> 6] = local;
  __syncthreads();
  if (threadIdx.x == 0) {
    int t = sm[0] + sm[1] + sm[2] + sm[3];
    if (t) atomicAdd(cnt, t);
  }
}

// Vectorized: 4 elements per thread. n4 = n/4 (n divisible by 4 for N*64 inputs).
__global__ __launch_bounds__(256)
void k_convert_x(const void* __restrict__ xin, bf16* __restrict__ xb,
                 const int* __restrict__ cnt, int n4) {
  int i = blockIdx.x * 256 + threadIdx.x;
  if (i >= n4) return;
  ushort4 o;
  if (*cnt > SNIFF_THRESH) {
    float4 v = ((const float4*)xin)[i];
    o.x = f2bu(v.x); o.y = f2bu(v.y); o.z = f2bu(v.z); o.w = f2bu(v.w);
  } else {
    o = ((const ushort4*)xin)[i];
  }
  ((ushort4*)xb)[i] = o;
}

// W^T-concat: wt[n*384 + si*64 + kk] = W_si[kk][n]; bsum[n] = sum_si b_si[n] (fp32)
__global__ void k_convert_w(const void* W0, const void* W1, const void* W2,
                            const void* W3, const void* W4, const void* W5,
                            const void* c0, const void* c1, const void* c2,
                            const void* c3, const void* c4, const void* c5,
                            bf16* __restrict__ wt, float* __restrict__ bsum,
                            const int* __restrict__ cnt) {
  int t = blockIdx.x * 256 + threadIdx.x;
  const void* Ws[6] = {W0, W1, W2, W3, W4, W5};
  const void* Bs[6] = {c0, c1, c2, c3, c4, c5};
  bool fp = (*cnt > SNIFF_THRESH);
  if (t < 6 * 4096) {
    int si = t >> 12, o = t & 4095;
    int kk = o >> 6, n = o & 63;
    float v = fp ? ((const float*)Ws[si])[o] : __bfloat162float(((const bf16*)Ws[si])[o]);
    wt[n * KTOT + si * 64 + kk] = __float2bfloat16(v);
  } else if (t < 6 * 4096 + 64) {
    int n = t - 6 * 4096;
    float s = 0.f;
    for (int si = 0; si < 6; si++)
      s += fp ? ((const float*)Bs[si])[n] : __bfloat162float(((const bf16*)Bs[si])[n]);
    bsum[n] = s;
  }
}

// ---------- CSR build via LDS counting sort (no global atomics) ----------
__global__ __launch_bounds__(256)
void k_hist(const int* __restrict__ row, const int* __restrict__ col,
            int* __restrict__ hist, int E, int NB, int NBLK) {
  __shared__ int hr[MAXNB], hc[MAXNB];
  for (int i = threadIdx.x; i < NB; i += 256) { hr[i] = 0; hc[i] = 0; }
  __syncthreads();
  int base = blockIdx.x << 11;
  for (int k = 0; k < 8; k++) {
    int e = base + k * 256 + threadIdx.x;
    if (e < E) {
      atomicAdd(&hr[row[e] >> 7], 1);
      atomicAdd(&hc[col[e] >> 7], 1);
    }
  }
  __syncthreads();
  for (int i = threadIdx.x; i < NB; i += 256) {
    hist[(size_t)i * NBLK + blockIdx.x] = hr[i];
    hist[(size_t)(NB + i) * NBLK + blockIdx.x] = hc[i];
  }
}

__global__ void k_scan_block(const int* __restrict__ in, int* __restrict__ out,
                             int* __restrict__ part, int n) {
  __shared__ int sm[256];
  int tid = threadIdx.x;
  int i = blockIdx.x * 256 + tid;
  int v = (i < n) ? in[i] : 0;
  sm[tid] = v;
  __syncthreads();
  for (int d = 1; d < 256; d <<= 1) {
    int t = (tid >= d) ? sm[tid - d] : 0;
    __syncthreads();
    if (tid >= d) sm[tid] += t;
    __syncthreads();
  }
  if (i < n) out[i] = sm[tid] - v;
  if (tid == 255) part[blockIdx.x] = sm[255];
}

__global__ void k_scan_part(int* part, int nb) {
  __shared__ int sm[1024];
  int tid = threadIdx.x;
  int v = (tid < nb) ? part[tid] : 0;
  sm[tid] = v;
  __syncthreads();
  for (int d = 1; d < 1024; d <<= 1) {
    int t = (tid >= d) ? sm[tid - d] : 0;
    __syncthreads();
    if (tid >= d) sm[tid] += t;
    __syncthreads();
  }
  if (tid < nb) part[tid] = sm[tid] - v;
}

__global__ void k_scan_add(int* __restrict__ out, const int* __restrict__ part, int n) {
  int i = blockIdx.x * 256 + threadIdx.x;
  if (i < n) out[i] += part[blockIdx.x];
}

__global__ __launch_bounds__(256)
void k_bucket_scatter(const int* __restrict__ row, const int* __restrict__ col,
                      const int* __restrict__ hist, int* __restrict__ packed,
                      int E, int NB, int NBLK) {
  __shared__ int br[MAXNB], bc[MAXNB];
  for (int i = threadIdx.x; i < NB; i += 256) {
    br[i] = hist[(size_t)i * NBLK + blockIdx.x];
    bc[i] = hist[(size_t)(NB + i) * NBLK + blockIdx.x];
  }
  __syncthreads();
  int base = blockIdx.x << 11;
  for (int k = 0; k < 8; k++) {
    int e = base + k * 256 + threadIdx.x;
    if (e < E) {
      int r = row[e], c = col[e];
      int pr = atomicAdd(&br[r >> 7], 1);
      packed[pr] = (c << 7) | (r & 127);
      int pc = atomicAdd(&bc[c >> 7], 1);
      packed[pc] = (r << 7) | (c & 127);
    }
  }
}

// One block per (direction, bucket): per-node counts -> deg2 fields, offsets, sorted adj.
__global__ __launch_bounds__(256)
void k_bucket_csr(const int* __restrict__ hist, const int* __restrict__ packed,
                  int* __restrict__ adj, int2* __restrict__ deg2,
                  int* __restrict__ roff, int* __restrict__ coff,
                  int N, int NB, int NBLK, int E2) {
  __shared__ int cnt[128], scn[128], cur[128];
  int gb = blockIdx.x;            // combined bucket index in [0, 2*NB)
  int tid = threadIdx.x;
  if (tid < 128) { cnt[tid] = 0; cur[tid] = 0; }
  __syncthreads();
  int start = hist[(size_t)gb * NBLK];
  int end = (gb + 1 < gridDim.x) ? hist[(size_t)(gb + 1) * NBLK] : E2;
  for (int i = start + tid; i < end; i += 256)
    atomicAdd(&cnt[packed[i] & 127], 1);
  __syncthreads();
  if (tid == 0) {
    int a = 0;
    for (int i = 0; i < 128; i++) { scn[i] = a; a += cnt[i]; }
  }
  __syncthreads();
  if (tid < 128) {
    int b = gb < NB ? gb : gb - NB;
    int node = (b << 7) + tid;
    if (node < N) {
      if (gb < NB) { deg2[node].x = cnt[tid]; roff[node] = start + scn[tid]; }
      else         { deg2[node].y = cnt[tid]; coff[node] = start + scn[tid]; }
    }
  }
  __syncthreads();
  for (int i = start + tid; i < end; i += 256) {
    int v = packed[i];
    int l = v & 127, o = v >> 7;
    int rk = atomicAdd(&cur[l], 1);
    adj[start + scn[l] + rk] = o;
  }
}

// Second-order degree sums (CSR gathers of packed int2 degrees) + packed scale vectors.
// sclG1[n] = {isi, sAtA, sAAi, iso}; sclG2[n] = {iso, sAAt, sAAo, isi}
__global__ __launch_bounds__(256)
void k_m4scales(const int* __restrict__ roff, const int* __restrict__ coff,
                const int2* __restrict__ deg2, const int* __restrict__ adj,
                float4* __restrict__ sclG1, float4* __restrict__ sclG2, int N) {
  int n = blockIdx.x * 256 + threadIdx.x;
  if (n >= N) return;
  int2 dn = deg2[n];
  int o0 = roff[n];
  float aat = 0.f, aao = 0.f;
  for (int e = 0; e < dn.x; e++) {
    int2 dc = deg2[adj[o0 + e]];
    aat += (float)dc.y;   // Av(d_in)
    aao += (float)dc.x;   // Av(d_out)
  }
  int i0 = coff[n];
  float ata = 0.f, aai = 0.f;
  for (int e = 0; e < dn.y; e++) {
    int2 dr = deg2[adj[i0 + e]];
    ata += (float)dr.x;   // Atv(d_out)
    aai += (float)dr.y;   // Atv(d_in)
  }
  float iso = inv_sqrt_pos((float)dn.x), isi = inv_sqrt_pos((float)dn.y);
  sclG1[n] = make_float4(isi, inv_sqrt_pos(ata), inv_sqrt_pos(aai), iso);
  sclG2[n] = make_float4(iso, inv_sqrt_pos(aat), inv_sqrt_pos(aao), isi);
}

// ---------- fused first-order passes: A (out-CSR/Av) + B (in-CSR/Atv) ----------
// A: P1 -> H slot0 (*iso); Q2 -> QR2 cols0-63; R1 -> QR1 cols64-127
// B: P2 -> H slot1 (*isi); Q1 -> QR1 cols0-63; R2 -> QR2 cols64-127
__global__ __launch_bounds__(256)
void k_passAB(const int* __restrict__ roff, const int* __restrict__ coff,
              const int2* __restrict__ deg2, const int* __restrict__ adj,
              const bf16* __restrict__ xb,
              const float4* __restrict__ sclG1, const float4* __restrict__ sclG2,
              bf16* __restrict__ H, bf16* __restrict__ QR1, bf16* __restrict__ QR2,
              int N, int gW) {
  int side = (blockIdx.x >= gW);
  int lb = side ? blockIdx.x - gW : blockIdx.x;
  int wid = (lb * 256 + (int)threadIdx.x) >> 6;
  if (wid >= N) return;
  int lane = threadIdx.x & 63;
  int q = lane >> 4, t4 = (lane & 15) << 2;
  int o, d; const float4* sclG; bf16 *outP, *outOwn, *outOth;
  if (!side) { o = roff[wid]; d = deg2[wid].x; sclG = sclG1;
               outP = H + 0 * 64; outOwn = QR2; outOth = QR1; }
  else       { o = coff[wid]; d = deg2[wid].y; sclG = sclG2;
               outP = H + 1 * 64; outOwn = QR1; outOth = QR2; }
  float a0[4] = {0,0,0,0}, a1[4] = {0,0,0,0}, a2[4] = {0,0,0,0};
  for (int e = q; e < d; e += 4) {
    int nb = adj[o + e];
    ushort4 r = *(const ushort4*)(xb + (size_t)nb * FDIM + t4);
    float4 s = sclG[nb];
    float f0 = us2f(r.x), f1 = us2f(r.y), f2 = us2f(r.z), f3 = us2f(r.w);
    a0[0] += s.x * f0; a0[1] += s.x * f1; a0[2] += s.x * f2; a0[3] += s.x * f3;
    a1[0] += s.y * f0; a1[1] += s.y * f1; a1[2] += s.y * f2; a1[3] += s.y * f3;
    a2[0] += s.z * f0; a2[1] += s.z * f1; a2[2] += s.z * f2; a2[3] += s.z * f3;
  }
  #pragma unroll
  for (int i = 0; i < 4; i++) {
    a0[i] += __shfl_xor(a0[i], 16); a0[i] += __shfl_xor(a0[i], 32);
    a1[i] += __shfl_xor(a1[i], 16); a1[i] += __shfl_xor(a1[i], 32);
    a2[i] += __shfl_xor(a2[i], 16); a2[i] += __shfl_xor(a2[i], 32);
  }
  if (q == 0) {
    float w = sclG[wid].w;
    ushort4 uP, uQ, uR;
    uP.x = f2bu(a0[0]*w); uP.y = f2bu(a0[1]*w); uP.z = f2bu(a0[2]*w); uP.w = f2bu(a0[3]*w);
    uQ.x = f2bu(a1[0]);   uQ.y = f2bu(a1[1]);   uQ.z = f2bu(a1[2]);   uQ.w = f2bu(a1[3]);
    uR.x = f2bu(a2[0]);   uR.y = f2bu(a2[1]);   uR.z = f2bu(a2[2]);   uR.w = f2bu(a2[3]);
    *(ushort4*)(outP + (size_t)wid * KTOT + t4) = uP;
    *(ushort4*)(outOwn + (size_t)wid * 128 + t4) = uQ;
    *(ushort4*)(outOth + (size_t)wid * 128 + 64 + t4) = uR;
  }
}

// ---------- fused second-order passes: C (out-CSR, QR1) + D (in-CSR, QR2) ----------
// One contiguous 256B gather per edge (16 lanes x uint4).
// C: S0=sAAt*Av(Q1)->slot2, S2=sAAo*Av(R1)->slot4;  D: S1=sAtA*Atv(Q2)->slot3, S3=sAAi*Atv(R2)->slot5
__global__ __launch_bounds__(256)
void k_passCD(const int* __restrict__ roff, const int* __restrict__ coff,
              const int2* __restrict__ deg2, const int* __restrict__ adj,
              const bf16* __restrict__ QR1, const bf16* __restrict__ QR2,
              const float4* __restrict__ sclG1, const float4* __restrict__ sclG2,
              bf16* __restrict__ H, int N, int gW) {
  int side = (blockIdx.x >= gW);   // 0 = C, 1 = D
  int lb = side ? blockIdx.x - gW : blockIdx.x;
  int wid = (lb * 256 + (int)threadIdx.x) >> 6;
  if (wid >= N) return;
  int lane = threadIdx.x & 63;
  int q = lane >> 4, t = lane & 15;
  int o, d; const bf16* QR;
  if (!side) { o = roff[wid]; d = deg2[wid].x; QR = QR1; }
  else       { o = coff[wid]; d = deg2[wid].y; QR = QR2; }
  float acc[8] = {0,0,0,0,0,0,0,0};
  for (int e = q; e < d; e += 4) {
    int nb = adj[o + e];
    uint4 v = *(const uint4*)(QR + (size_t)nb * 128 + t * 8);
    acc[0] += us2f(v.x & 0xffff); acc[1] += us2f(v.x >> 16);
    acc[2] += us2f(v.y & 0xffff); acc[3] += us2f(v.y >> 16);
    acc[4] += us2f(v.z & 0xffff); acc[5] += us2f(v.z >> 16);
    acc[6] += us2f(v.w & 0xffff); acc[7] += us2f(v.w >> 16);
  }
  #pragma unroll
  for (int i = 0; i < 8; i++) {
    acc[i] += __shfl_xor(acc[i], 16);
    acc[i] += __shfl_xor(acc[i], 32);
  }
  if (q == 0) {
    float4 s = side ? sclG1[wid] : sclG2[wid];
    float ws = (t < 8) ? s.y : s.z;
    int slot = side ? (t < 8 ? 3 : 5) : (t < 8 ? 2 : 4);
    int col = slot * 64 + (t & 7) * 8;
    uint4 ov;
    ov.x = pack2(acc[0]*ws, acc[1]*ws);
    ov.y = pack2(acc[2]*ws, acc[3]*ws);
    ov.z = pack2(acc[4]*ws, acc[5]*ws);
    ov.w = pack2(acc[6]*ws, acc[7]*ws);
    *(uint4*)(H + (size_t)wid * KTOT + col) = ov;
  }
}

// ---------- final MFMA GEMM: out[N,64] = 0.75*(H[N,384] @ Wcat[384,64] + bsum) ----------
__global__ __launch_bounds__(256)
void k_final(const bf16* __restrict__ H, const bf16* __restrict__ wt,
             const float* __restrict__ bsum, void* __restrict__ outv,
             const int* __restrict__ cnt, int N) {
  __shared__ bf16 Wl[64 * LDSK];
  {
    const unsigned int* wtu = (const unsigned int*)wt;
    unsigned int* wlu = (unsigned int*)Wl;
    for (int i = threadIdx.x; i < 64 * (KTOT / 2); i += 256) {
      int n = i / (KTOT / 2), k2 = i % (KTOT / 2);
      wlu[n * (LDSK / 2) + k2] = wtu[i];
    }
  }
  __syncthreads();

  int wave = threadIdx.x >> 6, lane = threadIdx.x & 63;
  int m0 = blockIdx.x * 64 + wave * 16;
  int ml = lane & 15, kq = lane >> 4;
  const bf16* Hrow = H + (size_t)(m0 + ml) * KTOT + kq * 8;

  f32x4 acc[4] = {{0,0,0,0},{0,0,0,0},{0,0,0,0},{0,0,0,0}};
  #pragma unroll
  for (int kb = 0; kb < KTOT / 32; kb++) {
    bf16x8 a = *(const bf16x8*)(Hrow + kb * 32);
    #pragma unroll
    for (int ct = 0; ct < 4; ct++) {
      bf16x8 b = *(const bf16x8*)(Wl + (size_t)(ct * 16 + ml) * LDSK + kb * 32 + kq * 8);
      acc[ct] = __builtin_amdgcn_mfma_f32_16x16x32_bf16(a, b, acc[ct], 0, 0, 0);
    }
  }

  bool fp = (*cnt > SNIFF_THRESH);
  #pragma unroll
  for (int ct = 0; ct < 4; ct++) {
    int col = ct * 16 + ml;
    float bias = bsum[col];
    #pragma unroll
    for (int r = 0; r < 4; r++) {
      int m = m0 + kq * 4 + r;
      if (m < N) {
        float val = 0.75f * (acc[ct][r] + bias);
        if (fp) ((float*)outv)[(size_t)m * FDIM + col] = val;
        else    ((bf16*)outv)[(size_t)m * FDIM + col] = __float2bfloat16(val);
      }
    }
  }
}

// ---------- host ----------
extern "C" void kernel_launch(void* const* d_in, const int* in_sizes, int n_in,
                              void* d_out, int out_size, void* d_ws, size_t ws_size,
                              hipStream_t stream) {
  const void* x = d_in[0];
  const int* ei = (const int*)d_in[1];
  int NX = in_sizes[0];
  int N = NX / FDIM;
  int E = in_sizes[1] / 2;
  const int* row = ei;
  const int* col = ei + E;

  char* p = (char*)d_ws;
  auto alloc = [&](size_t bytes) {
    bytes = (bytes + 255) & ~(size_t)255;
    char* r = p; p += bytes; return r;
  };

  int*   cnt  = (int*)alloc(4);            // zero-init region start
  int2*  deg2 = (int2*)alloc((size_t)N * 8);
  int* roff   = (int*)alloc((size_t)N * 4);
  int* coff   = (int*)alloc((size_t)N * 4);
  int* p1     = (int*)alloc(8192 * 4);
  int* p2     = (int*)alloc(1024 * 4);
  float4* sclG1 = (float4*)alloc((size_t)N * 16);
  float4* sclG2 = (float4*)alloc((size_t)N * 16);
  int* adj    = (int*)alloc((size_t)2 * E * 4);  // [0,E)=out-CSR, [E,2E)=in-CSR
  bf16* xb    = (bf16*)alloc((size_t)NX * 2);
  bf16* wt    = (bf16*)alloc((size_t)6 * 4096 * 2);
  float* bsum = (float*)alloc(64 * 4);
  bf16* H   = (bf16*)alloc((size_t)N * KTOT * 2); // 6 concatenated 64-col slots
  bf16* QR1 = (bf16*)alloc((size_t)N * 128 * 2);  // [Q1 | R1]
  bf16* QR2 = (bf16*)alloc((size_t)N * 128 * 2);  // [Q2 | R2]

  // dead-before-use aliases (consumed in CSR build, before QR1/H are written)
  int* hist   = (int*)QR1;  // 2*NB*NBLK ints (~4.9 MB <= 25.6 MB)
  int* packed = (int*)H;    // 2*E ints (12.8 MB <= 76.8 MB)

  hipMemsetAsync(d_ws, 0, 256, stream);

  int gN = (N + 255) / 256;
  int gW = (N + 3) / 4;      // wave-per-node kernels: 4 waves/block
  int gF = (N + 63) / 64;

  int NB   = (N + 127) >> 7;
  int NBLK = (E + 2047) >> 11;
  int lenH = 2 * NB * NBLK;
  int g0 = (lenH + 255) / 256;
  int g1 = (g0 + 255) / 256;

  // dtype canonicalization (sampled sniff: 1M elements, 1 atomic/block)
  int nSniff = NX < (1 << 20) ? NX : (1 << 20);
  k_sniff<<<256, 256, 0, stream>>>((const unsigned short*)x, nSniff, cnt);
  int n4 = NX / 4;
  k_convert_x<<<(n4 + 255) / 256, 256, 0, stream>>>(x, xb, cnt, n4);
  k_convert_w<<<98, 256, 0, stream>>>(d_in[2], d_in[4], d_in[6], d_in[8], d_in[10], d_in[12],
                                      d_in[3], d_in[5], d_in[7], d_in[9], d_in[11], d_in[13],
                                      wt, bsum, cnt);

  // CSR build: histogram -> scan -> bucket scatter -> per-bucket sort (no global atomics)
  k_hist<<<NBLK, 256, 0, stream>>>(row, col, hist, E, NB, NBLK);
  k_scan_block<<<g0, 256, 0, stream>>>(hist, hist, p1, lenH);
  k_scan_block<<<g1, 256, 0, stream>>>(p1, p1, p2, g0);
  k_scan_part<<<1, 1024, 0, stream>>>(p2, g1);
  k_scan_add<<<g1, 256, 0, stream>>>(p1, p2, g0);
  k_scan_add<<<g0, 256, 0, stream>>>(hist, p1, lenH);
  k_bucket_scatter<<<NBLK, 256, 0, stream>>>(row, col, hist, packed, E, NB, NBLK);
  k_bucket_csr<<<2 * NB, 256, 0, stream>>>(hist, packed, adj, deg2, roff, coff,
                                           N, NB, NBLK, 2 * E);
  k_m4scales<<<gN, 256, 0, stream>>>(roff, coff, deg2, adj, sclG1, sclG2, N);

  // fused first-order (A+B) and second-order (C+D) passes
  k_passAB<<<2 * gW, 256, 0, stream>>>(roff, coff, deg2, adj, xb, sclG1, sclG2,
                                       H, QR1, QR2, N, gW);
  k_passCD<<<2 * gW, 256, 0, stream>>>(roff, coff, deg2, adj, QR1, QR2, sclG1, sclG2,
                                       H, N, gW);

  // out = 0.75 * (H @ Wcat + bsum)
  k_final<<<gF, 256, 0, stream>>>(H, wt, bsum, d_out, cnt, N);
}

// Round 10
// 534.150 us; speedup vs baseline: 4.7091x; 1.0247x over previous
//
#include <hip/hip_runtime.h>
#include <hip/hip_bf16.h>

typedef __hip_bfloat16 bf16;
typedef __bf16 bf16x8 __attribute__((ext_vector_type(8)));
typedef float f32x4 __attribute__((ext_vector_type(4)));
#define FDIM 64
#define KTOT 384
#define LDSK 392   // padded K-stride for W^T in LDS
#define SNIFF_THRESH 100
#define MAXNB 1024 // max node buckets (supports N <= 131072; here N=100K -> 782)
#define EBLK 8192  // edges per CSR-build block
#define KITER (EBLK / 256)

__device__ __forceinline__ float us2f(unsigned short u) {
  union { unsigned int i; float f; } v; v.i = ((unsigned int)u) << 16; return v.f;
}
__device__ __forceinline__ unsigned short f2bu(float v) {
  bf16 h = __float2bfloat16(v);
  return *(unsigned short*)&h;
}
__device__ __forceinline__ unsigned int pack2(float a, float b) {
  return (unsigned int)f2bu(a) | ((unsigned int)f2bu(b) << 16);
}
__device__ __forceinline__ float inv_sqrt_pos(float d) { return d > 0.f ? rsqrtf(d) : 0.f; }

// ---------- dtype sniffing & canonicalization ----------
__global__ __launch_bounds__(256)
void k_sniff(const unsigned short* __restrict__ xs, int n, int* __restrict__ cnt) {
  int local = 0;
  for (int i = blockIdx.x * 256 + threadIdx.x; i < n; i += 256 * 256)
    local += ((xs[i] & 0x7F80) == 0x7F80) ? 1 : 0;
  #pragma unroll
  for (int d = 32; d >= 1; d >>= 1) local += __shfl_down(local, d);
  __shared__ int sm[4];
  if ((threadIdx.x & 63) == 0) sm[threadIdx.x >> 6] = local;
  __syncthreads();
  if (threadIdx.x == 0) {
    int t = sm[0] + sm[1] + sm[2] + sm[3];
    if (t) atomicAdd(cnt, t);
  }
}

// Vectorized: 4 elements per thread. n4 = n/4.
__global__ __launch_bounds__(256)
void k_convert_x(const void* __restrict__ xin, bf16* __restrict__ xb,
                 const int* __restrict__ cnt, int n4) {
  int i = blockIdx.x * 256 + threadIdx.x;
  if (i >= n4) return;
  ushort4 o;
  if (*cnt > SNIFF_THRESH) {
    float4 v = ((const float4*)xin)[i];
    o.x = f2bu(v.x); o.y = f2bu(v.y); o.z = f2bu(v.z); o.w = f2bu(v.w);
  } else {
    o = ((const ushort4*)xin)[i];
  }
  ((ushort4*)xb)[i] = o;
}

// W^T-concat: wt[n*384 + si*64 + kk] = W_si[kk][n]; bsum[n] = sum_si b_si[n] (fp32)
__global__ void k_convert_w(const void* W0, const void* W1, const void* W2,
                            const void* W3, const void* W4, const void* W5,
                            const void* c0, const void* c1, const void* c2,
                            const void* c3, const void* c4, const void* c5,
                            bf16* __restrict__ wt, float* __restrict__ bsum,
                            const int* __restrict__ cnt) {
  int t = blockIdx.x * 256 + threadIdx.x;
  const void* Ws[6] = {W0, W1, W2, W3, W4, W5};
  const void* Bs[6] = {c0, c1, c2, c3, c4, c5};
  bool fp = (*cnt > SNIFF_THRESH);
  if (t < 6 * 4096) {
    int si = t >> 12, o = t & 4095;
    int kk = o >> 6, n = o & 63;
    float v = fp ? ((const float*)Ws[si])[o] : __bfloat162float(((const bf16*)Ws[si])[o]);
    wt[n * KTOT + si * 64 + kk] = __float2bfloat16(v);
  } else if (t < 6 * 4096 + 64) {
    int n = t - 6 * 4096;
    float s = 0.f;
    for (int si = 0; si < 6; si++)
      s += fp ? ((const float*)Bs[si])[n] : __bfloat162float(((const bf16*)Bs[si])[n]);
    bsum[n] = s;
  }
}

// ---------- CSR build via LDS counting sort (no global atomics) ----------
__global__ __launch_bounds__(256)
void k_hist(const int* __restrict__ row, const int* __restrict__ col,
            int* __restrict__ hist, int E, int NB, int NBLK) {
  __shared__ int hr[MAXNB], hc[MAXNB];
  for (int i = threadIdx.x; i < NB; i += 256) { hr[i] = 0; hc[i] = 0; }
  __syncthreads();
  int base = blockIdx.x * EBLK;
  for (int k = 0; k < KITER; k++) {
    int e = base + k * 256 + threadIdx.x;
    if (e < E) {
      atomicAdd(&hr[row[e] >> 7], 1);
      atomicAdd(&hc[col[e] >> 7], 1);
    }
  }
  __syncthreads();
  for (int i = threadIdx.x; i < NB; i += 256) {
    hist[(size_t)i * NBLK + blockIdx.x] = hr[i];
    hist[(size_t)(NB + i) * NBLK + blockIdx.x] = hc[i];
  }
}

__global__ void k_scan_block(const int* __restrict__ in, int* __restrict__ out,
                             int* __restrict__ part, int n) {
  __shared__ int sm[256];
  int tid = threadIdx.x;
  int i = blockIdx.x * 256 + tid;
  int v = (i < n) ? in[i] : 0;
  sm[tid] = v;
  __syncthreads();
  for (int d = 1; d < 256; d <<= 1) {
    int t = (tid >= d) ? sm[tid - d] : 0;
    __syncthreads();
    if (tid >= d) sm[tid] += t;
    __syncthreads();
  }
  if (i < n) out[i] = sm[tid] - v;
  if (tid == 255) part[blockIdx.x] = sm[255];
}

__global__ void k_scan_part(int* part, int nb) {
  __shared__ int sm[1024];
  int tid = threadIdx.x;
  int v = (tid < nb) ? part[tid] : 0;
  sm[tid] = v;
  __syncthreads();
  for (int d = 1; d < 1024; d <<= 1) {
    int t = (tid >= d) ? sm[tid - d] : 0;
    __syncthreads();
    if (tid >= d) sm[tid] += t;
    __syncthreads();
  }
  if (tid < nb) part[tid] = sm[tid] - v;
}

__global__ void k_scan_add(int* __restrict__ out, const int* __restrict__ part, int n) {
  int i = blockIdx.x * 256 + threadIdx.x;
  if (i < n) out[i] += part[blockIdx.x];
}

__global__ __launch_bounds__(256)
void k_bucket_scatter(const int* __restrict__ row, const int* __restrict__ col,
                      const int* __restrict__ hist, int* __restrict__ packed,
                      int E, int NB, int NBLK) {
  __shared__ int br[MAXNB], bc[MAXNB];
  for (int i = threadIdx.x; i < NB; i += 256) {
    br[i] = hist[(size_t)i * NBLK + blockIdx.x];
    bc[i] = hist[(size_t)(NB + i) * NBLK + blockIdx.x];
  }
  __syncthreads();
  int base = blockIdx.x * EBLK;
  for (int k = 0; k < KITER; k++) {
    int e = base + k * 256 + threadIdx.x;
    if (e < E) {
      int r = row[e], c = col[e];
      int pr = atomicAdd(&br[r >> 7], 1);
      packed[pr] = (c << 7) | (r & 127);
      int pc = atomicAdd(&bc[c >> 7], 1);
      packed[pc] = (r << 7) | (c & 127);
    }
  }
}

// One block per (direction, bucket): per-node counts -> deg2 fields, offsets, sorted adj.
__global__ __launch_bounds__(256)
void k_bucket_csr(const int* __restrict__ hist, const int* __restrict__ packed,
                  int* __restrict__ adj, int2* __restrict__ deg2,
                  int* __restrict__ roff, int* __restrict__ coff,
                  int N, int NB, int NBLK, int E2) {
  __shared__ int cnt[128], scn[128], cur[128];
  int gb = blockIdx.x;            // combined bucket index in [0, 2*NB)
  int tid = threadIdx.x;
  if (tid < 128) { cnt[tid] = 0; cur[tid] = 0; }
  __syncthreads();
  int start = hist[(size_t)gb * NBLK];
  int end = (gb + 1 < gridDim.x) ? hist[(size_t)(gb + 1) * NBLK] : E2;
  for (int i = start + tid; i < end; i += 256)
    atomicAdd(&cnt[packed[i] & 127], 1);
  __syncthreads();
  if (tid == 0) {
    int a = 0;
    for (int i = 0; i < 128; i++) { scn[i] = a; a += cnt[i]; }
  }
  __syncthreads();
  if (tid < 128) {
    int b = gb < NB ? gb : gb - NB;
    int node = (b << 7) + tid;
    if (node < N) {
      if (gb < NB) { deg2[node].x = cnt[tid]; roff[node] = start + scn[tid]; }
      else         { deg2[node].y = cnt[tid]; coff[node] = start + scn[tid]; }
    }
  }
  __syncthreads();
  for (int i = start + tid; i < end; i += 256) {
    int v = packed[i];
    int l = v & 127, o = v >> 7;
    int rk = atomicAdd(&cur[l], 1);
    adj[start + scn[l] + rk] = o;
  }
}

// Second-order degree sums (CSR gathers of packed int2 degrees) + packed scale vectors.
// sclG1[n] = {isi, sAtA, sAAi, iso}; sclG2[n] = {iso, sAAt, sAAo, isi}
__global__ __launch_bounds__(256)
void k_m4scales(const int* __restrict__ roff, const int* __restrict__ coff,
                const int2* __restrict__ deg2, const int* __restrict__ adj,
                float4* __restrict__ sclG1, float4* __restrict__ sclG2, int N) {
  int n = blockIdx.x * 256 + threadIdx.x;
  if (n >= N) return;
  int2 dn = deg2[n];
  int o0 = roff[n];
  float aat = 0.f, aao = 0.f;
  for (int e = 0; e < dn.x; e++) {
    int2 dc = deg2[adj[o0 + e]];
    aat += (float)dc.y;   // Av(d_in)
    aao += (float)dc.x;   // Av(d_out)
  }
  int i0 = coff[n];
  float ata = 0.f, aai = 0.f;
  for (int e = 0; e < dn.y; e++) {
    int2 dr = deg2[adj[i0 + e]];
    ata += (float)dr.x;   // Atv(d_out)
    aai += (float)dr.y;   // Atv(d_in)
  }
  float iso = inv_sqrt_pos((float)dn.x), isi = inv_sqrt_pos((float)dn.y);
  sclG1[n] = make_float4(isi, inv_sqrt_pos(ata), inv_sqrt_pos(aai), iso);
  sclG2[n] = make_float4(iso, inv_sqrt_pos(aat), inv_sqrt_pos(aao), isi);
}

// ---------- fused first-order passes: A (out-CSR/Av) + B (in-CSR/Atv) ----------
// A: P1 -> H slot0 (*iso); Q2 -> QR2 cols0-63; R1 -> QR1 cols64-127
// B: P2 -> H slot1 (*isi); Q1 -> QR1 cols0-63; R2 -> QR2 cols64-127
__global__ __launch_bounds__(256, 8)
void k_passAB(const int* __restrict__ roff, const int* __restrict__ coff,
              const int2* __restrict__ deg2, const int* __restrict__ adj,
              const bf16* __restrict__ xb,
              const float4* __restrict__ sclG1, const float4* __restrict__ sclG2,
              bf16* __restrict__ H, bf16* __restrict__ QR1, bf16* __restrict__ QR2,
              int N, int gW) {
  int side = (blockIdx.x >= gW);
  int lb = side ? blockIdx.x - gW : blockIdx.x;
  int wid = (lb * 256 + (int)threadIdx.x) >> 6;
  if (wid >= N) return;
  int lane = threadIdx.x & 63;
  int q = lane >> 4, t4 = (lane & 15) << 2;
  int o, d; const float4* sclG; bf16 *outP, *outOwn, *outOth;
  if (!side) { o = roff[wid]; d = deg2[wid].x; sclG = sclG1;
               outP = H + 0 * 64; outOwn = QR2; outOth = QR1; }
  else       { o = coff[wid]; d = deg2[wid].y; sclG = sclG2;
               outP = H + 1 * 64; outOwn = QR1; outOth = QR2; }
  float a0[4] = {0,0,0,0}, a1[4] = {0,0,0,0}, a2[4] = {0,0,0,0};
  for (int e = q; e < d; e += 4) {
    int nb = adj[o + e];
    ushort4 r = *(const ushort4*)(xb + (size_t)nb * FDIM + t4);
    float4 s = sclG[nb];
    float f0 = us2f(r.x), f1 = us2f(r.y), f2 = us2f(r.z), f3 = us2f(r.w);
    a0[0] += s.x * f0; a0[1] += s.x * f1; a0[2] += s.x * f2; a0[3] += s.x * f3;
    a1[0] += s.y * f0; a1[1] += s.y * f1; a1[2] += s.y * f2; a1[3] += s.y * f3;
    a2[0] += s.z * f0; a2[1] += s.z * f1; a2[2] += s.z * f2; a2[3] += s.z * f3;
  }
  #pragma unroll
  for (int i = 0; i < 4; i++) {
    a0[i] += __shfl_xor(a0[i], 16); a0[i] += __shfl_xor(a0[i], 32);
    a1[i] += __shfl_xor(a1[i], 16); a1[i] += __shfl_xor(a1[i], 32);
    a2[i] += __shfl_xor(a2[i], 16); a2[i] += __shfl_xor(a2[i], 32);
  }
  if (q == 0) {
    float w = sclG[wid].w;
    ushort4 uP, uQ, uR;
    uP.x = f2bu(a0[0]*w); uP.y = f2bu(a0[1]*w); uP.z = f2bu(a0[2]*w); uP.w = f2bu(a0[3]*w);
    uQ.x = f2bu(a1[0]);   uQ.y = f2bu(a1[1]);   uQ.z = f2bu(a1[2]);   uQ.w = f2bu(a1[3]);
    uR.x = f2bu(a2[0]);   uR.y = f2bu(a2[1]);   uR.z = f2bu(a2[2]);   uR.w = f2bu(a2[3]);
    *(ushort4*)(outP + (size_t)wid * KTOT + t4) = uP;
    *(ushort4*)(outOwn + (size_t)wid * 128 + t4) = uQ;
    *(ushort4*)(outOth + (size_t)wid * 128 + 64 + t4) = uR;
  }
}

// ---------- fused second-order passes: C (out-CSR, QR1) + D (in-CSR, QR2) ----------
// One contiguous 256B gather per edge (16 lanes x uint4).
// C: S0=sAAt*Av(Q1)->slot2, S2=sAAo*Av(R1)->slot4;  D: S1=sAtA*Atv(Q2)->slot3, S3=sAAi*Atv(R2)->slot5
__global__ __launch_bounds__(256, 8)
void k_passCD(const int* __restrict__ roff, const int* __restrict__ coff,
              const int2* __restrict__ deg2, const int* __restrict__ adj,
              const bf16* __restrict__ QR1, const bf16* __restrict__ QR2,
              const float4* __restrict__ sclG1, const float4* __restrict__ sclG2,
              bf16* __restrict__ H, int N, int gW) {
  int side = (blockIdx.x >= gW);   // 0 = C, 1 = D
  int lb = side ? blockIdx.x - gW : blockIdx.x;
  int wid = (lb * 256 + (int)threadIdx.x) >> 6;
  if (wid >= N) return;
  int lane = threadIdx.x & 63;
  int q = lane >> 4, t = lane & 15;
  int o, d; const bf16* QR;
  if (!side) { o = roff[wid]; d = deg2[wid].x; QR = QR1; }
  else       { o = coff[wid]; d = deg2[wid].y; QR = QR2; }
  float acc[8] = {0,0,0,0,0,0,0,0};
  for (int e = q; e < d; e += 4) {
    int nb = adj[o + e];
    uint4 v = *(const uint4*)(QR + (size_t)nb * 128 + t * 8);
    acc[0] += us2f(v.x & 0xffff); acc[1] += us2f(v.x >> 16);
    acc[2] += us2f(v.y & 0xffff); acc[3] += us2f(v.y >> 16);
    acc[4] += us2f(v.z & 0xffff); acc[5] += us2f(v.z >> 16);
    acc[6] += us2f(v.w & 0xffff); acc[7] += us2f(v.w >> 16);
  }
  #pragma unroll
  for (int i = 0; i < 8; i++) {
    acc[i] += __shfl_xor(acc[i], 16);
    acc[i] += __shfl_xor(acc[i], 32);
  }
  if (q == 0) {
    float4 s = side ? sclG1[wid] : sclG2[wid];
    float ws = (t < 8) ? s.y : s.z;
    int slot = side ? (t < 8 ? 3 : 5) : (t < 8 ? 2 : 4);
    int col = slot * 64 + (t & 7) * 8;
    uint4 ov;
    ov.x = pack2(acc[0]*ws, acc[1]*ws);
    ov.y = pack2(acc[2]*ws, acc[3]*ws);
    ov.z = pack2(acc[4]*ws, acc[5]*ws);
    ov.w = pack2(acc[6]*ws, acc[7]*ws);
    *(uint4*)(H + (size_t)wid * KTOT + col) = ov;
  }
}

// ---------- final MFMA GEMM: out[N,64] = 0.75*(H[N,384] @ Wcat[384,64] + bsum) ----------
__global__ __launch_bounds__(256)
void k_final(const bf16* __restrict__ H, const bf16* __restrict__ wt,
             const float* __restrict__ bsum, void* __restrict__ outv,
             const int* __restrict__ cnt, int N) {
  __shared__ bf16 Wl[64 * LDSK];
  {
    const unsigned int* wtu = (const unsigned int*)wt;
    unsigned int* wlu = (unsigned int*)Wl;
    for (int i = threadIdx.x; i < 64 * (KTOT / 2); i += 256) {
      int n = i / (KTOT / 2), k2 = i % (KTOT / 2);
      wlu[n * (LDSK / 2) + k2] = wtu[i];
    }
  }
  __syncthreads();

  int wave = threadIdx.x >> 6, lane = threadIdx.x & 63;
  int m0 = blockIdx.x * 64 + wave * 16;
  int ml = lane & 15, kq = lane >> 4;
  const bf16* Hrow = H + (size_t)(m0 + ml) * KTOT + kq * 8;

  f32x4 acc[4] = {{0,0,0,0},{0,0,0,0},{0,0,0,0},{0,0,0,0}};
  #pragma unroll
  for (int kb = 0; kb < KTOT / 32; kb++) {
    bf16x8 a = *(const bf16x8*)(Hrow + kb * 32);
    #pragma unroll
    for (int ct = 0; ct < 4; ct++) {
      bf16x8 b = *(const bf16x8*)(Wl + (size_t)(ct * 16 + ml) * LDSK + kb * 32 + kq * 8);
      acc[ct] = __builtin_amdgcn_mfma_f32_16x16x32_bf16(a, b, acc[ct], 0, 0, 0);
    }
  }

  bool fp = (*cnt > SNIFF_THRESH);
  #pragma unroll
  for (int ct = 0; ct < 4; ct++) {
    int col = ct * 16 + ml;
    float bias = bsum[col];
    #pragma unroll
    for (int r = 0; r < 4; r++) {
      int m = m0 + kq * 4 + r;
      if (m < N) {
        float val = 0.75f * (acc[ct][r] + bias);
        if (fp) ((float*)outv)[(size_t)m * FDIM + col] = val;
        else    ((bf16*)outv)[(size_t)m * FDIM + col] = __float2bfloat16(val);
      }
    }
  }
}

// ---------- host ----------
extern "C" void kernel_launch(void* const* d_in, const int* in_sizes, int n_in,
                              void* d_out, int out_size, void* d_ws, size_t ws_size,
                              hipStream_t stream) {
  const void* x = d_in[0];
  const int* ei = (const int*)d_in[1];
  int NX = in_sizes[0];
  int N = NX / FDIM;
  int E = in_sizes[1] / 2;
  const int* row = ei;
  const int* col = ei + E;

  char* p = (char*)d_ws;
  auto alloc = [&](size_t bytes) {
    bytes = (bytes + 255) & ~(size_t)255;
    char* r = p; p += bytes; return r;
  };

  int*   cnt  = (int*)alloc(4);            // zero-init region start
  int2*  deg2 = (int2*)alloc((size_t)N * 8);
  int* roff   = (int*)alloc((size_t)N * 4);
  int* coff   = (int*)alloc((size_t)N * 4);
  int* p1     = (int*)alloc(8192 * 4);
  int* p2     = (int*)alloc(1024 * 4);
  float4* sclG1 = (float4*)alloc((size_t)N * 16);
  float4* sclG2 = (float4*)alloc((size_t)N * 16);
  int* adj    = (int*)alloc((size_t)2 * E * 4);  // [0,E)=out-CSR, [E,2E)=in-CSR
  bf16* xb    = (bf16*)alloc((size_t)NX * 2);
  bf16* wt    = (bf16*)alloc((size_t)6 * 4096 * 2);
  float* bsum = (float*)alloc(64 * 4);
  bf16* H   = (bf16*)alloc((size_t)N * KTOT * 2); // 6 concatenated 64-col slots
  bf16* QR1 = (bf16*)alloc((size_t)N * 128 * 2);  // [Q1 | R1]
  bf16* QR2 = (bf16*)alloc((size_t)N * 128 * 2);  // [Q2 | R2]

  // dead-before-use aliases (consumed in CSR build, before QR1/H are written)
  int* hist   = (int*)QR1;  // 2*NB*NBLK ints (~1.2 MB <= 25.6 MB)
  int* packed = (int*)H;    // 2*E ints (12.8 MB <= 76.8 MB)

  hipMemsetAsync(d_ws, 0, 256, stream);

  int gN = (N + 255) / 256;
  int gW = (N + 3) / 4;      // wave-per-node kernels: 4 waves/block
  int gF = (N + 63) / 64;

  int NB   = (N + 127) >> 7;
  int NBLK = (E + EBLK - 1) / EBLK;
  int lenH = 2 * NB * NBLK;
  int g0 = (lenH + 255) / 256;
  int g1 = (g0 + 255) / 256;

  // dtype canonicalization (sampled sniff: 1M elements, 1 atomic/block)
  int nSniff = NX < (1 << 20) ? NX : (1 << 20);
  k_sniff<<<256, 256, 0, stream>>>((const unsigned short*)x, nSniff, cnt);
  int n4 = NX / 4;
  k_convert_x<<<(n4 + 255) / 256, 256, 0, stream>>>(x, xb, cnt, n4);
  k_convert_w<<<98, 256, 0, stream>>>(d_in[2], d_in[4], d_in[6], d_in[8], d_in[10], d_in[12],
                                      d_in[3], d_in[5], d_in[7], d_in[9], d_in[11], d_in[13],
                                      wt, bsum, cnt);

  // CSR build: histogram -> scan -> bucket scatter -> per-bucket sort (no global atomics)
  k_hist<<<NBLK, 256, 0, stream>>>(row, col, hist, E, NB, NBLK);
  k_scan_block<<<g0, 256, 0, stream>>>(hist, hist, p1, lenH);
  k_scan_block<<<g1, 256, 0, stream>>>(p1, p1, p2, g0);
  k_scan_part<<<1, 1024, 0, stream>>>(p2, g1);
  k_scan_add<<<g1, 256, 0, stream>>>(p1, p2, g0);
  k_scan_add<<<g0, 256, 0, stream>>>(hist, p1, lenH);
  k_bucket_scatter<<<NBLK, 256, 0, stream>>>(row, col, hist, packed, E, NB, NBLK);
  k_bucket_csr<<<2 * NB, 256, 0, stream>>>(hist, packed, adj, deg2, roff, coff,
                                           N, NB, NBLK, 2 * E);
  k_m4scales<<<gN, 256, 0, stream>>>(roff, coff, deg2, adj, sclG1, sclG2, N);

  // fused first-order (A+B) and second-order (C+D) passes
  k_passAB<<<2 * gW, 256, 0, stream>>>(roff, coff, deg2, adj, xb, sclG1, sclG2,
                                       H, QR1, QR2, N, gW);
  k_passCD<<<2 * gW, 256, 0, stream>>>(roff, coff, deg2, adj, QR1, QR2, sclG1, sclG2,
                                       H, N, gW);

  // out = 0.75 * (H @ Wcat + bsum)
  k_final<<<gF, 256, 0, stream>>>(H, wt, bsum, d_out, cnt, N);
}